// Round 11
// baseline (5972.791 us; speedup 1.0000x reference)
//
#include <hip/hip_runtime.h>
#include <cmath>

#define DM 512
#define DH 64

typedef __attribute__((ext_vector_type(8))) short short8;
typedef __attribute__((ext_vector_type(4))) float float4v;

__device__ inline float b2f(unsigned short u){
  union{unsigned int i; float f;} z; z.i = ((unsigned)u)<<16; return z.f;
}
__device__ inline unsigned short f2b(float f){
  unsigned int x = __float_as_uint(f);
  return (unsigned short)((x + 0x7fffu + ((x>>16)&1u)) >> 16);   // RNE
}

#define GLL(gp, lp) __builtin_amdgcn_global_load_lds((const __attribute__((address_space(1))) void*)(gp), \
    (__attribute__((address_space(3))) void*)(lp), 16, 0, 0)

// ---------------- Threefry-2x32-20 (matches jax.random) ----------------
__host__ __device__ inline void tf2x32(unsigned k0, unsigned k1, unsigned& x0, unsigned& x1){
  const unsigned ks0=k0, ks1=k1, ks2=k0^k1^0x1BD11BDAu;
  x0 += ks0; x1 += ks1;
#define TF_ROT(r) { x0 += x1; x1 = (x1<<(r))|(x1>>(32-(r))); x1 ^= x0; }
  TF_ROT(13) TF_ROT(15) TF_ROT(26) TF_ROT(6)
  x0 += ks1; x1 += ks2 + 1u;
  TF_ROT(17) TF_ROT(29) TF_ROT(16) TF_ROT(24)
  x0 += ks2; x1 += ks0 + 2u;
  TF_ROT(13) TF_ROT(15) TF_ROT(26) TF_ROT(6)
  x0 += ks0; x1 += ks1 + 3u;
  TF_ROT(17) TF_ROT(29) TF_ROT(16) TF_ROT(24)
  x0 += ks1; x1 += ks2 + 4u;
  TF_ROT(13) TF_ROT(15) TF_ROT(26) TF_ROT(6)
  x0 += ks2; x1 += ks0 + 5u;
#undef TF_ROT
}

__global__ __launch_bounds__(256) void idx_kernel(int* __restrict__ idx, unsigned k2a, unsigned k2b,
                                                  int S2, int Lmask){
  int j = blockIdx.x*256 + threadIdx.x;
  if (j >= S2) return;
  unsigned x0 = (unsigned)j, x1 = (unsigned)(S2 + j);
  tf2x32(k2a, k2b, x0, x1);
  idx[j]      = (int)(x0 & (unsigned)Lmask);
  idx[S2 + j] = (int)(x1 & (unsigned)Lmask);
}

// ---------------- positional-embedding table ----------------
__global__ __launch_bounds__(256) void pe_kernel(float* __restrict__ pe, int L){
  int i = blockIdx.x*256 + threadIdx.x;
  int d = i % DM, l = i / DM;
  const float scale = -0.017988946f;  // -ln(10000)/512
  float freq = expf((float)(d & ~1) * scale);
  float ang  = (float)l * freq;
  pe[i] = (d & 1) ? cosf(ang) : sinf(ang);
}

// ---------------- transpose token-conv weights ----------------
__global__ __launch_bounds__(256) void packtcw(const float* __restrict__ tcw, float* __restrict__ tcwT){
  int i = blockIdx.x*256 + threadIdx.x;
  if (i >= 21*DM) return;
  int j = i / DM, d = i % DM;
  tcwT[(size_t)j*DM + d] = tcw[(size_t)d*21 + (j%7)*3 + (j/7)];
}

// ---------------- token embed ----------------
__global__ __launch_bounds__(256) void embed2(const float* __restrict__ x, const float* __restrict__ tcwT,
                                              const float* __restrict__ pe, float* __restrict__ h, int L){
  int row = blockIdx.x; int l = row % L, b = row / L;
  __shared__ float xs[21];
  int t = threadIdx.x;
  if (t < 21){
    int c = t % 7, kk = t / 7;
    int ls = l + kk - 1; ls = (ls < 0) ? ls + L : (ls >= L ? ls - L : ls);
    xs[t] = x[((size_t)b*L + ls)*7 + c];
  }
  __syncthreads();
  for (int d = t; d < DM; d += 256){
    float acc = 0.f;
#pragma unroll
    for (int j=0;j<21;j++) acc += xs[j]*tcwT[j*DM + d];
    h[(size_t)row*DM + d] = acc + pe[(size_t)l*DM + d];
  }
}

// ---------------- fp32 -> bf16 conversion (weights) ----------------
__global__ __launch_bounds__(256) void f2b_vec(const float* __restrict__ src, unsigned short* __restrict__ dst, int n4){
  int i = blockIdx.x*256 + threadIdx.x;
  if (i >= n4) return;
  float4 v = ((const float4*)src)[i];
  ushort4 o; o.x = f2b(v.x); o.y = f2b(v.y); o.z = f2b(v.z); o.w = f2b(v.w);
  ((ushort4*)dst)[i] = o;
}

// ---------------- pack conv weights along K ----------------
__global__ __launch_bounds__(256) void packconv(const float* __restrict__ dcw, unsigned short* __restrict__ wtapK){
  int i = blockIdx.x*256 + threadIdx.x;
  if (i >= 3*DM*DM) return;
  int n = i / (3*DM); int rem = i % (3*DM); int tap = rem / DM; int c = rem % DM;
  wtapK[(size_t)n*(3*DM) + tap*DM + c] = f2b(dcw[((size_t)n*DM + c)*3 + tap]);
}

// ---------------- concat qkv bias ----------------
__global__ __launch_bounds__(256) void catb_kernel(const float* __restrict__ a, const float* __restrict__ b,
    const float* __restrict__ c, float* __restrict__ o){
  int i = blockIdx.x*256 + threadIdx.x;
  if (i >= 1536) return;
  o[i] = (i < 512) ? a[i] : (i < 1024 ? b[i-512] : c[i-1024]);
}

// ---------------- per-row LN stats of (h + cw): rst[row] = {mu, rstd} ----------------
__global__ __launch_bounds__(256) void rowstats_kernel(const float* __restrict__ h, const float* __restrict__ cw,
                                                       float* __restrict__ rst, int L){
  int row = blockIdx.x*4 + (threadIdx.x >> 6);
  int lane = threadIdx.x & 63;
  int b = row / L;
  const float* p = h + (size_t)row*DM + lane*8;
  const float* c = cw + (size_t)b*DM + lane*8;
  float4 a0 = *(const float4*)p,     a1 = *(const float4*)(p+4);
  float4 c0 = *(const float4*)c,     c1 = *(const float4*)(c+4);
  float v[8] = {a0.x+c0.x, a0.y+c0.y, a0.z+c0.z, a0.w+c0.w,
                a1.x+c1.x, a1.y+c1.y, a1.z+c1.z, a1.w+c1.w};
  float s = 0.f, q = 0.f;
#pragma unroll
  for (int i=0;i<8;i++){ s += v[i]; q += v[i]*v[i]; }
#pragma unroll
  for (int off=32; off; off>>=1){ s += __shfl_xor(s,off); q += __shfl_xor(q,off); }
  if (lane == 0){
    float mu = s * (1.0f/DM);
    rst[(size_t)row*2]   = mu;
    rst[(size_t)row*2+1] = rsqrtf(q*(1.0f/DM) - mu*mu + 1e-5f);
  }
}

// =======================================================================
// bgemm2: bf16 MFMA GEMM, 128xTN, BK=64, single-buffered staging.
// A32: fp32 A, VGPR convert. LNA: fused LayerNorm(+cw) on A during staging.
// swz: XCD-aware L2-locality remap. convmode: 3-tap circular K=1536.
// qkv: route 512-col groups to bufstride-spaced buffers. act: tanh GELU.
// =======================================================================
template<int TN, int A32, int LNA>
__global__ __launch_bounds__(256) void bgemm2(const void* __restrict__ Ain,
    const unsigned short* __restrict__ Wb, const float* __restrict__ bias, void* __restrict__ C,
    int N, int K, int L, int convmode, int act, int outbf, int qkv, size_t bufstride, int swz,
    const float* __restrict__ rst, const float* __restrict__ cwv,
    const float* __restrict__ lng, const float* __restrict__ lnb, int row0g){
  constexpr int NJ = TN/32;
  constexpr int BR = TN/32;
  __shared__ unsigned short As[128*64];
  __shared__ unsigned short Bs[TN*64];
  int tid = threadIdx.x;
  int w = tid >> 6, ln = tid & 63;

  int bx = blockIdx.x, by = blockIdx.y;
  if (swz){
    int XT = gridDim.x, YT = gridDim.y;
    int lid = by*XT + bx;
    int xcd = lid & 7, s = lid >> 3;
    int ych = YT >> 3;
    int CHv = ych < 16 ? ych : 16;
    int yloc = s % CHv;
    int t2 = s / CHv;
    int xx = t2 % XT;
    int chunk = t2 / XT;
    by = xcd*ych + chunk*CHv + yloc;
    bx = xx;
  }
  int row0 = by*128, col0 = bx*TN;
  int KA = convmode ? 512 : K;

  long aBase[4], dPrev[4], dNext[4]; int aCol[4]; int growA[4];
#pragma unroll
  for (int g=0; g<4; g++){
    int ch = g*256 + tid;
    int r = ch >> 3, c = ch & 7;
    int gc = c ^ (r & 7);
    int gr = row0 + r;
    aCol[g] = gc*8;
    aBase[g] = (long)gr * KA;
    growA[g] = gr;
    if (convmode){
      int l = gr % L;
      dPrev[g] = (l==0)   ? (long)(L-1)*KA : -(long)KA;
      dNext[g] = (l==L-1) ? -(long)(L-1)*KA : (long)KA;
    } else { dPrev[g]=0; dNext[g]=0; }
  }
  float mu_[4], rs_[4]; int bofs_[4];
  if (LNA){
#pragma unroll
    for (int g=0; g<4; g++){
      mu_[g] = rst[(size_t)growA[g]*2];
      rs_[g] = rst[(size_t)growA[g]*2+1];
      bofs_[g] = ((row0g + growA[g]) / L) * DM;
    }
  }
  long bBase[BR];
#pragma unroll
  for (int g=0; g<BR; g++){
    int ch = g*256 + tid;
    int r = ch >> 3, c = ch & 7;
    int gc = c ^ (r & 7);
    bBase[g] = (long)(col0 + r)*K + gc*8;
  }
  int raBase[4], rbBase[NJ];
#pragma unroll
  for (int i=0;i<4;i++)  raBase[i] = ((w&1)*64 + i*16 + (ln&15))*8;
#pragma unroll
  for (int j=0;j<NJ;j++) rbBase[j] = ((w>>1)*(TN/2) + j*16 + (ln&15))*8;

  float4v acc[4][NJ] = {};
  int nIter = K/64;
  const unsigned short* A16 = (const unsigned short*)Ain;
  const float* Af = (const float*)Ain;

  for (int it=0; it<nIter; it++){
    int k0 = it*64;
    int kk = convmode ? (k0 & 511) : k0;
    int seg = convmode ? (k0 >> 9) : 1;
    if (A32){
#pragma unroll
      for (int g=0; g<4; g++){
        long d = convmode ? ((seg==0) ? dPrev[g] : (seg==2 ? dNext[g] : 0)) : 0;
        const float* src = Af + aBase[g] + d + kk + aCol[g];
        float4 v0 = *(const float4*)src;
        float4 v1 = *(const float4*)(src+4);
        if (LNA){
          int co = kk + aCol[g];
          float4 c0 = *(const float4*)(cwv + bofs_[g] + co);
          float4 c1 = *(const float4*)(cwv + bofs_[g] + co + 4);
          float4 g0 = *(const float4*)(lng + co);
          float4 g1 = *(const float4*)(lng + co + 4);
          float4 b0 = *(const float4*)(lnb + co);
          float4 b1 = *(const float4*)(lnb + co + 4);
          float mu = mu_[g], rs = rs_[g];
          v0.x = (v0.x + c0.x - mu)*rs*g0.x + b0.x;
          v0.y = (v0.y + c0.y - mu)*rs*g0.y + b0.y;
          v0.z = (v0.z + c0.z - mu)*rs*g0.z + b0.z;
          v0.w = (v0.w + c0.w - mu)*rs*g0.w + b0.w;
          v1.x = (v1.x + c1.x - mu)*rs*g1.x + b1.x;
          v1.y = (v1.y + c1.y - mu)*rs*g1.y + b1.y;
          v1.z = (v1.z + c1.z - mu)*rs*g1.z + b1.z;
          v1.w = (v1.w + c1.w - mu)*rs*g1.w + b1.w;
        }
        short8 pk;
        pk[0]=(short)f2b(v0.x); pk[1]=(short)f2b(v0.y); pk[2]=(short)f2b(v0.z); pk[3]=(short)f2b(v0.w);
        pk[4]=(short)f2b(v1.x); pk[5]=(short)f2b(v1.y); pk[6]=(short)f2b(v1.z); pk[7]=(short)f2b(v1.w);
        *(short8*)((char*)As + g*4096 + tid*16) = pk;
      }
    } else {
#pragma unroll
      for (int g=0; g<4; g++){
        long d = convmode ? ((seg==0) ? dPrev[g] : (seg==2 ? dNext[g] : 0)) : 0;
        GLL(A16 + aBase[g] + d + kk + aCol[g], (char*)As + g*4096 + w*1024);
      }
    }
#pragma unroll
    for (int g=0; g<BR; g++)
      GLL(Wb + bBase[g] + k0, (char*)Bs + g*4096 + w*1024);
    __syncthreads();
    const char* ab = (const char*)As;
    const char* bb = (const char*)Bs;
#pragma unroll
    for (int s=0;s<2;s++){
      int xs = (s*4 + (ln>>4)) ^ (ln&7);
      short8 af[4], bf[NJ];
#pragma unroll
      for (int i=0;i<4;i++)  af[i] = *(const short8*)(ab + (raBase[i] + xs)*16);
#pragma unroll
      for (int j=0;j<NJ;j++) bf[j] = *(const short8*)(bb + (rbBase[j] + xs)*16);
#pragma unroll
      for (int i=0;i<4;i++)
#pragma unroll
        for (int j=0;j<NJ;j++)
          acc[i][j] = __builtin_amdgcn_mfma_f32_16x16x32_bf16(af[i], bf[j], acc[i][j], 0, 0, 0);
    }
    __syncthreads();
  }

  float* Cf = (float*)C;
  unsigned short* Cb = (unsigned short*)C;
  int colb0 = col0 + (w>>1)*(TN/2) + (ln & 15);
#pragma unroll
  for (int i=0;i<4;i++){
#pragma unroll
    for (int r=0;r<4;r++){
      int grow = row0 + (w&1)*64 + i*16 + (ln>>4)*4 + r;
#pragma unroll
      for (int j=0;j<NJ;j++){
        int colb = colb0 + j*16;
        float v = acc[i][j][r];
        if (bias) v += bias[colb];
        if (act){
          float z = 0.7978845608f * v * (1.f + 0.044715f*v*v);
          float e = __expf(2.f*z);
          v = v * (1.f - 1.f/(e + 1.f));
        }
        if (outbf){
          if (qkv){
            int bsel = colb >> 9;
            Cb[(size_t)bsel*bufstride + (size_t)grow*512 + (colb & 511)] = f2b(v);
          } else {
            Cb[(size_t)grow*N + colb] = f2b(v);
          }
        } else {
          Cf[(size_t)grow*N + colb] = v;
        }
      }
    }
  }
}

// ---------------- sample_m2: one wave per (b,l), all 8 heads ----------------
__global__ __launch_bounds__(256) void sample_m2(const unsigned short* __restrict__ q,
    const unsigned short* __restrict__ k, const int* __restrict__ idx, float* __restrict__ m, int L, int u){
  int w = (blockIdx.x*256 + threadIdx.x) >> 6;
  int lane = threadIdx.x & 63;
  int l = w % L; int b = w / L;
  const unsigned short* qrow = q + (size_t)w*DM + lane*8;
  uint4 qq = *(const uint4*)qrow;
  float qv[8];
  qv[0]=b2f((unsigned short)(qq.x&0xffff)); qv[1]=b2f((unsigned short)(qq.x>>16));
  qv[2]=b2f((unsigned short)(qq.y&0xffff)); qv[3]=b2f((unsigned short)(qq.y>>16));
  qv[4]=b2f((unsigned short)(qq.z&0xffff)); qv[5]=b2f((unsigned short)(qq.z>>16));
  qv[6]=b2f((unsigned short)(qq.w&0xffff)); qv[7]=b2f((unsigned short)(qq.w>>16));
  const unsigned short* kb = k + (size_t)b*L*DM + lane*8;
  const int* ip = idx + (size_t)l*u;
  float mx = -1e30f, sum = 0.f;
  for (int s=0; s<u; s++){
    int kp = ip[s];
    uint4 kk = *(const uint4*)(kb + (size_t)kp*DM);
    float p;
    p  = qv[0]*b2f((unsigned short)(kk.x&0xffff)) + qv[1]*b2f((unsigned short)(kk.x>>16));
    p += qv[2]*b2f((unsigned short)(kk.y&0xffff)) + qv[3]*b2f((unsigned short)(kk.y>>16));
    p += qv[4]*b2f((unsigned short)(kk.z&0xffff)) + qv[5]*b2f((unsigned short)(kk.z>>16));
    p += qv[6]*b2f((unsigned short)(kk.w&0xffff)) + qv[7]*b2f((unsigned short)(kk.w>>16));
    p += __shfl_xor(p, 1); p += __shfl_xor(p, 2); p += __shfl_xor(p, 4);
    mx = fmaxf(mx, p); sum += p;
  }
  if ((lane & 7) == 0){
    int hh = lane >> 3;
    m[((size_t)b*8 + hh)*L + l] = mx - sum/(float)u;
  }
}

// ---------------- top-k stage A: per-segment local top-u ----------------
__global__ __launch_bounds__(256) void topkA(const float* __restrict__ m, float* __restrict__ cval,
    int* __restrict__ cidx, int L, int u){
  int bh = blockIdx.x, seg = blockIdx.y;
  int segL = L >> 3;
  int t = threadIdx.x;
  __shared__ float rv[256];
  __shared__ int   ri[256];
  float myv = (t < segL) ? m[(size_t)bh*L + seg*segL + t] : -1e31f;
  int   myi = seg*segL + t;
  for (int it=0; it<u; it++){
    rv[t] = myv; ri[t] = myi;
    __syncthreads();
    for (int s=128; s; s>>=1){
      if (t < s){
        float v2 = rv[t+s]; int i2 = ri[t+s];
        if (v2 > rv[t] || (v2 == rv[t] && i2 < ri[t])){ rv[t] = v2; ri[t] = i2; }
      }
      __syncthreads();
    }
    if (t == 0){
      cval[((size_t)bh*8 + seg)*u + it] = rv[0];
      cidx[((size_t)bh*8 + seg)*u + it] = ri[0];
    }
    __syncthreads();
    if (myi == ri[0]) myv = -1e31f;
    __syncthreads();
  }
}

// ---------------- top-k stage B: merge 8u candidates ----------------
__global__ __launch_bounds__(256) void topkB(const float* __restrict__ cval, const int* __restrict__ cidx,
    int* __restrict__ top, int u){
  int bh = blockIdx.x; int n = 8*u;
  int t = threadIdx.x;
  __shared__ float vals[320];
  __shared__ int   vidx[320];
  __shared__ float rv[256]; __shared__ int rg[256]; __shared__ int rs[256];
  for (int i=t; i<n; i+=256){ vals[i] = cval[(size_t)bh*n + i]; vidx[i] = cidx[(size_t)bh*n + i]; }
  __syncthreads();
  for (int it=0; it<u; it++){
    float bv = -1e31f; int bg = 0x7fffffff, bs = -1;
    for (int i=t; i<n; i+=256){
      float v = vals[i]; int gi = vidx[i];
      if (v > bv || (v == bv && gi < bg)){ bv = v; bg = gi; bs = i; }
    }
    rv[t] = bv; rg[t] = bg; rs[t] = bs;
    __syncthreads();
    for (int s=128; s; s>>=1){
      if (t < s){
        float v2 = rv[t+s]; int g2 = rg[t+s];
        if (v2 > rv[t] || (v2 == rv[t] && g2 < rg[t])){ rv[t]=v2; rg[t]=g2; rs[t]=rs[t+s]; }
      }
      __syncthreads();
    }
    if (t == 0){ top[(size_t)bh*u + it] = rg[0]; vals[rs[0]] = -1e31f; }
    __syncthreads();
  }
}

// ---------------- column mean, two-stage ----------------
#define CMC 32
__global__ __launch_bounds__(256) void colmean1(const float* __restrict__ src, float* __restrict__ part, int L){
  int b = blockIdx.x, ch = blockIdx.y;
  int rpb = L / CMC;
  int t = threadIdx.x;
  const float* p = src + ((size_t)b*L + (size_t)ch*rpb)*DM;
  float s0 = 0.f, s1 = 0.f;
  for (int r=0; r<rpb; r++){ s0 += p[(size_t)r*DM + t]; s1 += p[(size_t)r*DM + t + 256]; }
  float* o = part + ((size_t)b*CMC + ch)*DM;
  o[t] = s0; o[t+256] = s1;
}
__global__ __launch_bounds__(256) void colmean2(const float* __restrict__ part, float* __restrict__ dst, int L){
  int i = blockIdx.x*256 + threadIdx.x;
  int d = i % DM, b = i / DM;
  float s = 0.f;
  for (int c=0; c<CMC; c++) s += part[((size_t)b*CMC + c)*DM + d];
  dst[i] = s / (float)L;
}

// ---------------- tiny fp32 GEMM ----------------
__global__ __launch_bounds__(256) void tiny_gemm(const float* __restrict__ A, const float* __restrict__ W,
    const float* __restrict__ bias, float* __restrict__ C, int N, int K){
  int row = blockIdx.x;
  const float* ar = A + (size_t)row*K;
  __shared__ float as[DM];
  for (int k=threadIdx.x; k<K; k+=256) as[k] = ar[k];
  __syncthreads();
  for (int n = threadIdx.x; n < N; n += 256){
    float acc = bias ? bias[n] : 0.f;
    const float* wr = W + (size_t)n*K;
    for (int k=0; k<K; k++) acc += as[k]*wr[k];
    C[(size_t)row*N + n] = acc;
  }
}

// ---------------- gather q rows for top queries ----------------
__global__ __launch_bounds__(256) void qred_kernel(const unsigned short* __restrict__ q, const int* __restrict__ top,
    float* __restrict__ qred, int L, int u, int n){
  int i = blockIdx.x*256 + threadIdx.x;
  if (i >= n) return;
  int d = i & 63; int rest = i >> 6; int j = rest % u; int bh = rest / u;
  int hh = bh & 7; int b = bh >> 3;
  int pos = top[bh*u + j];
  qred[i] = b2f(q[((size_t)b*L + pos)*DM + hh*DH + d]);
}

// =======================================================================
// flash_attn: fused QK^T -> online softmax -> PV, key-split partials.
// =======================================================================
#define FKT 128
__global__ __launch_bounds__(256) void flash_attn(const float* __restrict__ qred,
    const unsigned short* __restrict__ kbuf, const unsigned short* __restrict__ vbuf,
    float* __restrict__ partM, float* __restrict__ partL, float* __restrict__ partA,
    int L, int u, int KS){
  int ks = blockIdx.x, bh = blockIdx.y; int b = bh >> 3, h = bh & 7;
  int t = threadIdx.x;
  __shared__ float Qs[38*64];
  __shared__ unsigned short Ks[FKT*64];
  __shared__ unsigned short Vs[FKT*64];
  __shared__ float Ss[38*FKT];
  for (int i=t;i<u*64;i+=256) Qs[i] = qred[(size_t)bh*u*64 + i];
  int lane = t & 63, w = t >> 6;
  float rm[10], rl[10], racc[10];
#pragma unroll
  for (int j=0;j<10;j++){ rm[j]=-1e30f; rl[j]=0.f; racc[j]=0.f; }
  int nk = L / KS;
  int kbase = ks*nk;
  int key = t & 127, rh = t >> 7;
  for (int kt = 0; kt < nk; kt += FKT){
    __syncthreads();
    for (int e = t; e < FKT*8; e += 256){
      int k = e >> 3, c = e & 7;
      size_t gidx = ((size_t)(b*L + kbase + kt + k))*DM + h*DH + c*8;
      *(uint4*)((char*)Ks + (size_t)(k*8 + (c ^ (k&7)))*16) = *(const uint4*)(kbuf + gidx);
      *(uint4*)((char*)Vs + (size_t)e*16) = *(const uint4*)(vbuf + gidx);
    }
    __syncthreads();
    for (int r = rh; r < u; r += 2){
      const float4* q4 = (const float4*)(Qs + r*64);
      float acc = 0.f;
#pragma unroll
      for (int c=0;c<8;c++){
        short8 kk = *(const short8*)((char*)Ks + (size_t)(key*8 + (c ^ (key&7)))*16);
        float4 qa = q4[c*2], qb = q4[c*2+1];
        acc += qa.x*b2f((unsigned short)kk[0]) + qa.y*b2f((unsigned short)kk[1])
             + qa.z*b2f((unsigned short)kk[2]) + qa.w*b2f((unsigned short)kk[3]);
        acc += qb.x*b2f((unsigned short)kk[4]) + qb.y*b2f((unsigned short)kk[5])
             + qb.z*b2f((unsigned short)kk[6]) + qb.w*b2f((unsigned short)kk[7]);
      }
      Ss[r*FKT + key] = acc * 0.125f;
    }
    __syncthreads();
    int j = 0;
    for (int r = w; r < u; r += 4, j++){
      float s0 = Ss[r*FKT + lane], s1 = Ss[r*FKT + 64 + lane];
      float mx = fmaxf(s0, s1);
#pragma unroll
      for (int off=32; off; off>>=1) mx = fmaxf(mx, __shfl_xor(mx, off));
      float newm = fmaxf(rm[j], mx);
      float scale = expf(rm[j] - newm);
      float p0 = expf(s0 - newm), p1 = expf(s1 - newm);
      float ps = p0 + p1;
#pragma unroll
      for (int off=32; off; off>>=1) ps += __shfl_xor(ps, off);
      rl[j] = rl[j]*scale + ps;
      rm[j] = newm;
      Ss[r*FKT + lane] = p0; Ss[r*FKT + 64 + lane] = p1;
      float a = racc[j]*scale;
      for (int k=0;k<FKT;k+=4){
        float pa = Ss[r*FKT+k], pb = Ss[r*FKT+k+1], pc = Ss[r*FKT+k+2], pd = Ss[r*FKT+k+3];
        a += pa*b2f(Vs[(k+0)*64+lane]) + pb*b2f(Vs[(k+1)*64+lane])
           + pc*b2f(Vs[(k+2)*64+lane]) + pd*b2f(Vs[(k+3)*64+lane]);
      }
      racc[j] = a;
    }
  }
  int j = 0;
  for (int r = w; r < u; r += 4, j++){
    size_t base = ((size_t)bh*KS + ks)*u + r;
    if (lane == 0){ partM[base] = rm[j]; partL[base] = rl[j]; }
    partA[base*64 + lane] = racc[j];
  }
}

// ---------------- fused merge + sparse residual scatter ----------------
__global__ __launch_bounds__(256) void fms_kernel(const float* __restrict__ partM, const float* __restrict__ partL,
    const float* __restrict__ partA, const float* __restrict__ vmean, const float* __restrict__ wo,
    const int* __restrict__ top, float* __restrict__ h, int L, int u, int KS, int gbase){
  int j = blockIdx.x % u; int bhl = blockIdx.x / u;
  int hh = bhl & 7; int bG = gbase + (bhl >> 3);
  int t = threadIdx.x;
  __shared__ float delta[DH];
  if (t < DH){
    size_t base0 = ((size_t)bhl*KS)*u + j;
    float gm = -1e30f;
    for (int s=0;s<KS;s++) gm = fmaxf(gm, partM[base0 + (size_t)s*u]);
    float lt = 0.f, at = 0.f;
    for (int s=0;s<KS;s++){
      float e = expf(partM[base0 + (size_t)s*u] - gm);
      lt += partL[base0 + (size_t)s*u]*e;
      at += partA[(base0 + (size_t)s*u)*64 + t]*e;
    }
    delta[t] = at/lt - vmean[(size_t)bG*DM + hh*DH + t];
  }
  __syncthreads();
  int pos = top[(size_t)bhl*u + j];
  float* hrow = h + ((size_t)bG*L + pos)*DM;
  const float* wbase = wo + hh*DH;
  for (int n = t; n < DM; n += 256){
    float acc = 0.f;
    const float* wr = wbase + (size_t)n*DM;
#pragma unroll
    for (int dd=0; dd<DH; dd++) acc += delta[dd] * wr[dd];
    atomicAdd(&hrow[n], acc);
  }
}

// ---------------- LayerNorm D=512 (LN2 path) ----------------
__global__ __launch_bounds__(256) void ln_kernel(const float* __restrict__ X, const void* __restrict__ Yadd,
    int yb, const float* __restrict__ g, const float* __restrict__ bta, void* __restrict__ Out, int ob,
    const float* __restrict__ cwv, int Lrow, int row0g){
  size_t row = blockIdx.x;
  const float* xr = X + row*DM;
  int t = threadIdx.x;
  float v0 = xr[t], v1 = xr[t+256];
  if (cwv){
    int b = (int)((row0g + (int)row) / Lrow);
    v0 += cwv[b*DM + t]; v1 += cwv[b*DM + t+256];
  }
  if (Yadd){
    if (yb){ const unsigned short* yr = (const unsigned short*)Yadd + row*DM; v0 += b2f(yr[t]); v1 += b2f(yr[t+256]); }
    else   { const float* yr = (const float*)Yadd + row*DM; v0 += yr[t]; v1 += yr[t+256]; }
  }
  float s = v0+v1, q = v0*v0+v1*v1;
#pragma unroll
  for (int off=32; off; off>>=1){ s += __shfl_xor(s,off); q += __shfl_xor(q,off); }
  __shared__ float ss[4], qq[4];
  int w = t >> 6;
  if ((t & 63) == 0){ ss[w] = s; qq[w] = q; }
  __syncthreads();
  s = ss[0]+ss[1]+ss[2]+ss[3]; q = qq[0]+qq[1]+qq[2]+qq[3];
  float mu  = s * (1.0f/DM);
  float var = q * (1.0f/DM) - mu*mu;
  float r = rsqrtf(var + 1e-5f);
  float o0 = (v0 - mu)*r*g[t]     + bta[t];
  float o1 = (v1 - mu)*r*g[t+256] + bta[t+256];
  if (ob){
    unsigned short* Ob = (unsigned short*)Out;
    Ob[row*DM + t] = f2b(o0); Ob[row*DM + t+256] = f2b(o1);
  } else {
    float* Of = (float*)Out;
    Of[row*DM + t] = o0; Of[row*DM + t+256] = o1;
  }
}

// ---------------- BN partial sums over bf16 conv output ----------------
__global__ __launch_bounds__(256) void bnstat1(const unsigned short* __restrict__ C, float* __restrict__ partS,
                                               float* __restrict__ partQ, int rpb){
  int chb = blockIdx.x;
  int mb  = blockIdx.y;
  int g = threadIdx.x >> 6, c = threadIdx.x & 63;
  int ch = chb*64 + c;
  float s = 0.f, q = 0.f;
  int r0 = mb * rpb;
  for (int r = r0 + g; r < r0 + rpb; r += 4){
    float v = b2f(C[(size_t)r*DM + ch]); s += v; q += v*v;
  }
  __shared__ float ls[4][64], lq[4][64];
  ls[g][c] = s; lq[g][c] = q;
  __syncthreads();
  if (g == 0){
    s = ls[0][c]+ls[1][c]+ls[2][c]+ls[3][c];
    q = lq[0][c]+lq[1][c]+lq[2][c]+lq[3][c];
    partS[(size_t)mb*DM + ch] = s;
    partQ[(size_t)mb*DM + ch] = q;
  }
}
__global__ __launch_bounds__(256) void bnstat2(const float* __restrict__ partS, const float* __restrict__ partQ,
                                               float* __restrict__ stats, int NB, int M){
  int ch = blockIdx.x*256 + threadIdx.x;
  if (ch >= DM) return;
  float s = 0.f, q = 0.f;
  for (int mb=0; mb<NB; mb++){
    s += partS[(size_t)mb*DM + ch];
    q += partQ[(size_t)mb*DM + ch];
  }
  float mu = s / (float)M;
  stats[ch] = mu;
  stats[DM + ch] = q / (float)M - mu*mu;
}

// ---------------- BN + ELU + maxpool(3,2) ----------------
__global__ __launch_bounds__(256) void bnpool(const unsigned short* __restrict__ C, const float* __restrict__ stats,
    const float* __restrict__ g, const float* __restrict__ bta, float* __restrict__ Out,
    int L, int Lo){
  size_t i = (size_t)blockIdx.x*256 + threadIdx.x;
  int ch = (int)(i % DM);
  size_t r = i / DM;
  int lo = (int)(r % Lo);
  int b  = (int)(r / Lo);
  float mu = stats[ch];
  float rstd = rsqrtf(stats[DM+ch] + 1e-5f);
  float gg = g[ch], bb = bta[ch];
  float best = -1e30f;
#pragma unroll
  for (int t=-1; t<=1; t++){
    int li = 2*lo + t;
    if (li >= 0 && li < L){
      float v = (b2f(C[((size_t)b*L + li)*DM + ch]) - mu)*rstd*gg + bb;
      v = v > 0.f ? v : expm1f(v);
      best = fmaxf(best, v);
    }
  }
  Out[((size_t)b*Lo + lo)*DM + ch] = best;
}

// ---------------- final: LN(last row) @ proj^T + proj_b + skip ----------------
__global__ __launch_bounds__(128) void final_kernel(const float* __restrict__ h, const float* __restrict__ x,
    const float* __restrict__ fg, const float* __restrict__ fb, const float* __restrict__ pw,
    const float* __restrict__ pb, const float* __restrict__ sw, const float* __restrict__ sb,
    float* __restrict__ out, int Lf, int L0){
  int b = blockIdx.x;
  const float* row = h + ((size_t)b*Lf + (Lf-1))*DM;
  __shared__ float xn[DM];
  __shared__ float rs[2], rq[2];
  int t = threadIdx.x;
  float v[4]; float s = 0.f, q = 0.f;
#pragma unroll
  for (int i=0;i<4;i++){ v[i] = row[t + i*128]; s += v[i]; q += v[i]*v[i]; }
#pragma unroll
  for (int off=32; off; off>>=1){ s += __shfl_xor(s,off); q += __shfl_xor(q,off); }
  if ((t & 63) == 0){ rs[t>>6] = s; rq[t>>6] = q; }
  __syncthreads();
  s = rs[0]+rs[1]; q = rq[0]+rq[1];
  float mu = s*(1.0f/DM), var = q*(1.0f/DM) - mu*mu;
  float r = rsqrtf(var + 1e-5f);
#pragma unroll
  for (int i=0;i<4;i++){ int d = t + i*128; xn[d] = (v[i]-mu)*r*fg[d] + fb[d]; }
  __syncthreads();
  if (t < 96){
    float acc = pb[t] + sb[t];
    const float* xr = x + ((size_t)b*L0 + (L0-1))*7;
#pragma unroll
    for (int c=0;c<7;c++) acc += xr[c]*sw[t*7+c];
    for (int d=0; d<DM; d++) acc += xn[d]*pw[(size_t)t*DM + d];
    out[b*96 + t] = acc;
  }
}

// =======================================================================
extern "C" void kernel_launch(void* const* d_in, const int* in_sizes, int n_in,
                              void* d_out, int out_size, void* d_ws, size_t ws_size,
                              hipStream_t stream){
  const float* x    = (const float*)d_in[0];
  const float* skw  = (const float*)d_in[1];
  const float* skb  = (const float*)d_in[2];
  const float* tcw  = (const float*)d_in[3];
  const float* wq   = (const float*)d_in[4];
  const float* bq   = (const float*)d_in[5];
  const float* wk   = (const float*)d_in[6];
  const float* bk   = (const float*)d_in[7];
  const float* wv   = (const float*)d_in[8];
  const float* bv   = (const float*)d_in[9];
  const float* wo   = (const float*)d_in[10];
  const float* bo   = (const float*)d_in[11];
  const float* w1   = (const float*)d_in[12];
  const float* b1   = (const float*)d_in[13];
  const float* w2   = (const float*)d_in[14];
  const float* b2   = (const float*)d_in[15];
  const float* ln1g = (const float*)d_in[16];
  const float* ln1b = (const float*)d_in[17];
  const float* ln2g = (const float*)d_in[18];
  const float* ln2b = (const float*)d_in[19];
  const float* dcw  = (const float*)d_in[20];
  const float* dcb  = (const float*)d_in[21];
  const float* bng  = (const float*)d_in[22];
  const float* bnb  = (const float*)d_in[23];
  const float* flg  = (const float*)d_in[24];
  const float* flb  = (const float*)d_in[25];
  const float* pw   = (const float*)d_in[26];
  const float* pb   = (const float*)d_in[27];

  const int B = 32, L0 = 2048, DFF = 2048;
  const int RG = 16384;
  const int RF = 8192;
  char* ws = (char*)d_ws;
  const size_t SZH  = (size_t)B*L0*DM*sizeof(float);
  const size_t SLOT = (size_t)RG*DM*sizeof(unsigned short);

  const size_t WBSZ = (size_t)(3*DM*DM + 2*DFF*DM + 3*DM*DM)*2;
  const size_t NCAND = (size_t)256*8*40;         // topk candidates: max bh(256) x 8 segs x u(<=40)
  size_t small_bytes = (size_t)L0*40*4
                     + (size_t)RG*8*4
                     + (size_t)B*8*40*4
                     + (size_t)32*8*40*64*4
                     + 3*(size_t)B*DM*4
                     + 2*(size_t)128*DM*4
                     + (size_t)2*DM*4
                     + (size_t)1536*4
                     + (size_t)B*CMC*DM*4
                     + (size_t)L0*DM*4
                     + (size_t)21*DM*4
                     + (size_t)B*L0*2*4          // rowstats
                     + 2*NCAND*4;                // topk candidates (val+idx)
  if (ws_size < SZH + 4*SLOT + WBSZ + small_bytes) return;

  float*          h   = (float*)(ws);
  unsigned short* P0  = (unsigned short*)(ws + SZH);
  unsigned short* P1  = (unsigned short*)(ws + SZH + SLOT);
  unsigned short* P2  = (unsigned short*)(ws + SZH + 2*SLOT);
  unsigned short* P3  = (unsigned short*)(ws + SZH + 3*SLOT);
  unsigned short* wb  = (unsigned short*)(ws + SZH + 4*SLOT);
  unsigned short* wqb = wb;
  unsigned short* w1b = wqb + (size_t)3*DM*DM;
  unsigned short* w2b = w1b + (size_t)DFF*DM;
  unsigned short* wtapK= w2b + (size_t)DM*DFF;
  char* sm = ws + SZH + 4*SLOT + WBSZ;
  int*   idx_buf  = (int*)sm;
  float* m_buf    = (float*)(sm + (size_t)L0*40*4);
  int*   top_all  = (int*)((char*)m_buf + (size_t)RG*8*4);
  float* qred_loc = (float*)((char*)top_all + (size_t)B*8*40*4);
  float* hm       = qred_loc + (size_t)32*8*40*64;
  float* vmean    = hm + (size_t)B*DM;
  float* cw       = vmean + (size_t)B*DM;
  float* partS    = cw + (size_t)B*DM;
  float* partQ    = partS + (size_t)128*DM;
  float* stats    = partQ + (size_t)128*DM;
  float* bqkv     = stats + (size_t)2*DM;
  float* partC    = bqkv + (size_t)1536;
  float* pe_buf   = partC + (size_t)B*CMC*DM;
  float* tcwT     = pe_buf + (size_t)L0*DM;
  float* rowstats = tcwT + (size_t)21*DM;                 // B*L0*2
  float* cvalB    = rowstats + (size_t)B*L0*2;            // NCAND
  int*   cidxB    = (int*)(cvalB + NCAND);                // NCAND

  // flash partials live in P0 (free during attention)
  float* fpM = (float*)P0;                       // (G*8)*KS*u <= 64*8*40
  float* fpL = fpM + (size_t)64*8*40;
  float* fpA = fpL + (size_t)64*8*40;            // *64 floats (~5.2 MB max)

  auto conv_b = [&](const float* src, unsigned short* dst, size_t n){
    f2b_vec<<<(int)((n/4 + 255)/256), 256, 0, stream>>>(src, dst, (int)(n/4));
  };

  pe_kernel<<<(int)(((size_t)L0*DM)/256), 256, 0, stream>>>(pe_buf, L0);
  packtcw<<<(21*DM + 255)/256, 256, 0, stream>>>(tcw, tcwT);
  embed2<<<B*L0, 256, 0, stream>>>(x, tcwT, pe_buf, h, L0);

  int L = L0;
  for (int layer = 0; layer < 3; layer++){
    int M = B * L;
    int u = (int)(5.0 * log((double)L + 1.0));   // 38 / 34 / 31
    int G = RG / L;
    int nG = M / RG;
    int KS = L / 256;                            // 8 / 4 / 2 key-splits
    const float* wv_i = wv + (size_t)layer*DM*DM;  const float* bv_i = bv + (size_t)layer*DM;
    const float* wo_i = wo + (size_t)layer*DM*DM;  const float* bo_i = bo + (size_t)layer*DM;
    const float* b1_i = b1 + (size_t)layer*DFF;
    const float* b2_i = b2 + (size_t)layer*DM;

    conv_b(wq + (size_t)layer*DM*DM, wqb,                    (size_t)DM*DM);
    conv_b(wk + (size_t)layer*DM*DM, wqb + (size_t)DM*DM,    (size_t)DM*DM);
    conv_b(wv_i,                     wqb + (size_t)2*DM*DM,  (size_t)DM*DM);
    conv_b(w1 + (size_t)layer*DFF*DM, w1b, (size_t)DFF*DM);
    conv_b(w2 + (size_t)layer*DM*DFF, w2b, (size_t)DM*DFF);
    catb_kernel<<<6, 256, 0, stream>>>(bq + (size_t)layer*DM, bk + (size_t)layer*DM, bv_i, bqkv);
    if (layer < 2)
      packconv<<<(3*DM*DM + 255)/256, 256, 0, stream>>>(dcw + (size_t)layer*DM*DM*3, wtapK);

    unsigned ka = 0u, kb2 = (unsigned)layer;
    tf2x32(0u, 42u, ka, kb2);
    unsigned a0 = 0u, a1 = 2u;  tf2x32(ka, kb2, a0, a1);
    unsigned c0 = 1u, c1 = 3u;  tf2x32(ka, kb2, c0, c1);
    int S2 = L * u / 2;
    idx_kernel<<<(S2 + 255)/256, 256, 0, stream>>>(idx_buf, a1, c1, S2, L-1);

    // vmean/cw first (exact fp32 identity), needed by fms + fused LN1
    colmean1<<<dim3(B, CMC), 256, 0, stream>>>(h, partC, L);
    colmean2<<<B*DM/256, 256, 0, stream>>>(partC, hm, L);
    tiny_gemm<<<B, 256, 0, stream>>>(hm, wv_i, bv_i, vmean, DM, DM);
    tiny_gemm<<<B, 256, 0, stream>>>(vmean, wo_i, bo_i, cw, DM, DM);

    for (int g = 0; g < nG; g++){
      const float* hg = h + (size_t)g*RG*DM;
      bgemm2<128,1,0><<<dim3(12, RG/128), 256, 0, stream>>>(hg, wqb, bqkv, P1,
          1536, 512, L, 0, 0, 1, 1, (size_t)RG*DM, 1, nullptr, nullptr, nullptr, nullptr, 0);
      sample_m2<<<RG/4, 256, 0, stream>>>(P1, P2, idx_buf, m_buf, L, u);
      int* top_g = top_all + (size_t)g*G*8*u;
      topkA<<<dim3(G*8, 8), 256, 0, stream>>>(m_buf, cvalB, cidxB, L, u);
      topkB<<<G*8, 256, 0, stream>>>(cvalB, cidxB, top_g, u);
      int nqr = G*8*u*DH;
      qred_kernel<<<(nqr + 255)/256, 256, 0, stream>>>(P1, top_g, qred_loc, L, u, nqr);

      flash_attn<<<dim3(KS, G*8), 256, 0, stream>>>(qred_loc, P2, P3, fpM, fpL, fpA, L, u, KS);
      fms_kernel<<<G*8*u, 256, 0, stream>>>(fpM, fpL, fpA, vmean, wo_i, top_g, h, L, u, KS, g*G);
    }

    // fused-LN1 row stats (over h + cw)
    rowstats_kernel<<<M/4, 256, 0, stream>>>(h, cw, rowstats, L);

    unsigned short* mid  = P1;                     // RF x 2048 bf16 (P1+P2)
    unsigned short* y2b  = P0;                     // RF x 512 bf16
    const float* l1g = ln1g + (size_t)layer*DM; const float* l1b = ln1b + (size_t)layer*DM;
    const float* l2g = ln2g + (size_t)layer*DM; const float* l2b = ln2b + (size_t)layer*DM;
    for (int r0 = 0; r0 < M; r0 += RF){
      bgemm2<128,1,1><<<dim3(16, RF/128), 256, 0, stream>>>(h + (size_t)r0*DM, w1b, b1_i, mid,
          2048, 512, L, 0, 1, 1, 0, 0, 1, rowstats + (size_t)r0*2, cw, l1g, l1b, r0);
      bgemm2<64,0,0><<<dim3(8, RF/128), 256, 0, stream>>>(mid, w2b, b2_i, y2b,
          512, 2048, L, 0, 0, 1, 0, 0, 1, nullptr, nullptr, nullptr, nullptr, 0);
      ln_kernel<<<RF, 256, 0, stream>>>(h + (size_t)r0*DM, y2b, 1, l2g, l2b, h + (size_t)r0*DM, 0, cw, L, r0);
    }

    if (layer < 2){
      const float* db = dcb + (size_t)layer*DM;
      unsigned short* convb = P0;
      bgemm2<64,1,0><<<dim3(8, M/128), 256, 0, stream>>>(h, wtapK, db, convb,
          512, 1536, L, 1, 0, 1, 0, 0, 1, nullptr, nullptr, nullptr, nullptr, 0);
      bnstat1<<<dim3(8, 128), 256, 0, stream>>>(convb, partS, partQ, M/128);
      bnstat2<<<2, 256, 0, stream>>>(partS, partQ, stats, 128, M);
      int Lo = L/2;
      bnpool<<<(int)(((size_t)B*Lo*DM)/256), 256, 0, stream>>>(convb, stats,
          bng + (size_t)layer*DM, bnb + (size_t)layer*DM, h, L, Lo);
      L = Lo;
    }
  }

  final_kernel<<<B, 128, 0, stream>>>(h, x, flg, flb, pw, pb, skw, skb, (float*)d_out, L, L0);
}

// Round 12
// 5607.046 us; speedup vs baseline: 1.0652x; 1.0652x over previous
//
#include <hip/hip_runtime.h>
#include <cmath>

#define DM 512
#define DH 64

typedef __attribute__((ext_vector_type(8))) short short8;
typedef __attribute__((ext_vector_type(4))) float float4v;

__device__ inline float b2f(unsigned short u){
  union{unsigned int i; float f;} z; z.i = ((unsigned)u)<<16; return z.f;
}
__device__ inline unsigned short f2b(float f){
  unsigned int x = __float_as_uint(f);
  return (unsigned short)((x + 0x7fffu + ((x>>16)&1u)) >> 16);   // RNE
}

#define GLL(gp, lp) __builtin_amdgcn_global_load_lds((const __attribute__((address_space(1))) void*)(gp), \
    (__attribute__((address_space(3))) void*)(lp), 16, 0, 0)

// ---------------- Threefry-2x32-20 (matches jax.random) ----------------
__host__ __device__ inline void tf2x32(unsigned k0, unsigned k1, unsigned& x0, unsigned& x1){
  const unsigned ks0=k0, ks1=k1, ks2=k0^k1^0x1BD11BDAu;
  x0 += ks0; x1 += ks1;
#define TF_ROT(r) { x0 += x1; x1 = (x1<<(r))|(x1>>(32-(r))); x1 ^= x0; }
  TF_ROT(13) TF_ROT(15) TF_ROT(26) TF_ROT(6)
  x0 += ks1; x1 += ks2 + 1u;
  TF_ROT(17) TF_ROT(29) TF_ROT(16) TF_ROT(24)
  x0 += ks2; x1 += ks0 + 2u;
  TF_ROT(13) TF_ROT(15) TF_ROT(26) TF_ROT(6)
  x0 += ks0; x1 += ks1 + 3u;
  TF_ROT(17) TF_ROT(29) TF_ROT(16) TF_ROT(24)
  x0 += ks1; x1 += ks2 + 4u;
  TF_ROT(13) TF_ROT(15) TF_ROT(26) TF_ROT(6)
  x0 += ks2; x1 += ks0 + 5u;
#undef TF_ROT
}

__global__ __launch_bounds__(256) void idx_kernel(int* __restrict__ idx, unsigned k2a, unsigned k2b,
                                                  int S2, int Lmask){
  int j = blockIdx.x*256 + threadIdx.x;
  if (j >= S2) return;
  unsigned x0 = (unsigned)j, x1 = (unsigned)(S2 + j);
  tf2x32(k2a, k2b, x0, x1);
  idx[j]      = (int)(x0 & (unsigned)Lmask);
  idx[S2 + j] = (int)(x1 & (unsigned)Lmask);
}

// ---------------- positional-embedding table ----------------
__global__ __launch_bounds__(256) void pe_kernel(float* __restrict__ pe, int L){
  int i = blockIdx.x*256 + threadIdx.x;
  int d = i % DM, l = i / DM;
  const float scale = -0.017988946f;  // -ln(10000)/512
  float freq = expf((float)(d & ~1) * scale);
  float ang  = (float)l * freq;
  pe[i] = (d & 1) ? cosf(ang) : sinf(ang);
}

// ---------------- transpose token-conv weights ----------------
__global__ __launch_bounds__(256) void packtcw(const float* __restrict__ tcw, float* __restrict__ tcwT){
  int i = blockIdx.x*256 + threadIdx.x;
  if (i >= 21*DM) return;
  int j = i / DM, d = i % DM;
  tcwT[(size_t)j*DM + d] = tcw[(size_t)d*21 + (j%7)*3 + (j/7)];
}

// ---------------- token embed ----------------
__global__ __launch_bounds__(256) void embed2(const float* __restrict__ x, const float* __restrict__ tcwT,
                                              const float* __restrict__ pe, float* __restrict__ h, int L){
  int row = blockIdx.x; int l = row % L, b = row / L;
  __shared__ float xs[21];
  int t = threadIdx.x;
  if (t < 21){
    int c = t % 7, kk = t / 7;
    int ls = l + kk - 1; ls = (ls < 0) ? ls + L : (ls >= L ? ls - L : ls);
    xs[t] = x[((size_t)b*L + ls)*7 + c];
  }
  __syncthreads();
  for (int d = t; d < DM; d += 256){
    float acc = 0.f;
#pragma unroll
    for (int j=0;j<21;j++) acc += xs[j]*tcwT[j*DM + d];
    h[(size_t)row*DM + d] = acc + pe[(size_t)l*DM + d];
  }
}

// ---------------- fp32 -> bf16 conversion (weights) ----------------
__global__ __launch_bounds__(256) void f2b_vec(const float* __restrict__ src, unsigned short* __restrict__ dst, int n4){
  int i = blockIdx.x*256 + threadIdx.x;
  if (i >= n4) return;
  float4 v = ((const float4*)src)[i];
  ushort4 o; o.x = f2b(v.x); o.y = f2b(v.y); o.z = f2b(v.z); o.w = f2b(v.w);
  ((ushort4*)dst)[i] = o;
}

// ---------------- pack conv weights along K ----------------
__global__ __launch_bounds__(256) void packconv(const float* __restrict__ dcw, unsigned short* __restrict__ wtapK){
  int i = blockIdx.x*256 + threadIdx.x;
  if (i >= 3*DM*DM) return;
  int n = i / (3*DM); int rem = i % (3*DM); int tap = rem / DM; int c = rem % DM;
  wtapK[(size_t)n*(3*DM) + tap*DM + c] = f2b(dcw[((size_t)n*DM + c)*3 + tap]);
}

// ---------------- concat qkv bias ----------------
__global__ __launch_bounds__(256) void catb_kernel(const float* __restrict__ a, const float* __restrict__ b,
    const float* __restrict__ c, float* __restrict__ o){
  int i = blockIdx.x*256 + threadIdx.x;
  if (i >= 1536) return;
  o[i] = (i < 512) ? a[i] : (i < 1024 ? b[i-512] : c[i-1024]);
}

// =======================================================================
// bgemm2: bf16 MFMA GEMM, 128xTN, BK=64, single-buffered staging.
// A32: fp32 A, VGPR convert. swz: XCD-aware L2-locality remap (CHv=8 for
// fp32 A so the hot row-set fits 4MB L2). convmode: 3-tap circular K=1536.
// qkv: route 512-col groups to bufstride-spaced buffers. act: tanh GELU.
// =======================================================================
template<int TN, int A32>
__global__ __launch_bounds__(256) void bgemm2(const void* __restrict__ Ain,
    const unsigned short* __restrict__ Wb, const float* __restrict__ bias, void* __restrict__ C,
    int N, int K, int L, int convmode, int act, int outbf, int qkv, size_t bufstride, int swz){
  constexpr int NJ = TN/32;
  constexpr int BR = TN/32;
  __shared__ unsigned short As[128*64];
  __shared__ unsigned short Bs[TN*64];
  int tid = threadIdx.x;
  int w = tid >> 6, ln = tid & 63;

  int bx = blockIdx.x, by = blockIdx.y;
  if (swz){
    int XT = gridDim.x, YT = gridDim.y;
    int lid = by*XT + bx;
    int xcd = lid & 7, s = lid >> 3;
    int ych = YT >> 3;
    int CHmax = A32 ? 8 : 16;                 // keep hot A rows <= 2MB per XCD L2
    int CHv = ych < CHmax ? ych : CHmax;
    int yloc = s % CHv;
    int t2 = s / CHv;
    int xx = t2 % XT;
    int chunk = t2 / XT;
    by = xcd*ych + chunk*CHv + yloc;
    bx = xx;
  }
  int row0 = by*128, col0 = bx*TN;
  int KA = convmode ? 512 : K;

  long aBase[4], dPrev[4], dNext[4]; int aCol[4];
#pragma unroll
  for (int g=0; g<4; g++){
    int ch = g*256 + tid;
    int r = ch >> 3, c = ch & 7;
    int gc = c ^ (r & 7);
    int gr = row0 + r;
    aCol[g] = gc*8;
    aBase[g] = (long)gr * KA;
    if (convmode){
      int l = gr % L;
      dPrev[g] = (l==0)   ? (long)(L-1)*KA : -(long)KA;
      dNext[g] = (l==L-1) ? -(long)(L-1)*KA : (long)KA;
    } else { dPrev[g]=0; dNext[g]=0; }
  }
  long bBase[BR];
#pragma unroll
  for (int g=0; g<BR; g++){
    int ch = g*256 + tid;
    int r = ch >> 3, c = ch & 7;
    int gc = c ^ (r & 7);
    bBase[g] = (long)(col0 + r)*K + gc*8;
  }
  int raBase[4], rbBase[NJ];
#pragma unroll
  for (int i=0;i<4;i++)  raBase[i] = ((w&1)*64 + i*16 + (ln&15))*8;
#pragma unroll
  for (int j=0;j<NJ;j++) rbBase[j] = ((w>>1)*(TN/2) + j*16 + (ln&15))*8;

  float4v acc[4][NJ] = {};
  int nIter = K/64;
  const unsigned short* A16 = (const unsigned short*)Ain;
  const float* Af = (const float*)Ain;

  for (int it=0; it<nIter; it++){
    int k0 = it*64;
    int kk = convmode ? (k0 & 511) : k0;
    int seg = convmode ? (k0 >> 9) : 1;
    if (A32){
#pragma unroll
      for (int g=0; g<4; g++){
        long d = convmode ? ((seg==0) ? dPrev[g] : (seg==2 ? dNext[g] : 0)) : 0;
        const float* src = Af + aBase[g] + d + kk + aCol[g];
        float4 v0 = *(const float4*)src;
        float4 v1 = *(const float4*)(src+4);
        short8 pk;
        pk[0]=(short)f2b(v0.x); pk[1]=(short)f2b(v0.y); pk[2]=(short)f2b(v0.z); pk[3]=(short)f2b(v0.w);
        pk[4]=(short)f2b(v1.x); pk[5]=(short)f2b(v1.y); pk[6]=(short)f2b(v1.z); pk[7]=(short)f2b(v1.w);
        *(short8*)((char*)As + g*4096 + tid*16) = pk;
      }
    } else {
#pragma unroll
      for (int g=0; g<4; g++){
        long d = convmode ? ((seg==0) ? dPrev[g] : (seg==2 ? dNext[g] : 0)) : 0;
        GLL(A16 + aBase[g] + d + kk + aCol[g], (char*)As + g*4096 + w*1024);
      }
    }
#pragma unroll
    for (int g=0; g<BR; g++)
      GLL(Wb + bBase[g] + k0, (char*)Bs + g*4096 + w*1024);
    __syncthreads();
    const char* ab = (const char*)As;
    const char* bb = (const char*)Bs;
#pragma unroll
    for (int s=0;s<2;s++){
      int xs = (s*4 + (ln>>4)) ^ (ln&7);
      short8 af[4], bf[NJ];
#pragma unroll
      for (int i=0;i<4;i++)  af[i] = *(const short8*)(ab + (raBase[i] + xs)*16);
#pragma unroll
      for (int j=0;j<NJ;j++) bf[j] = *(const short8*)(bb + (rbBase[j] + xs)*16);
#pragma unroll
      for (int i=0;i<4;i++)
#pragma unroll
        for (int j=0;j<NJ;j++)
          acc[i][j] = __builtin_amdgcn_mfma_f32_16x16x32_bf16(af[i], bf[j], acc[i][j], 0, 0, 0);
    }
    __syncthreads();
  }

  float* Cf = (float*)C;
  unsigned short* Cb = (unsigned short*)C;
  int colb0 = col0 + (w>>1)*(TN/2) + (ln & 15);
#pragma unroll
  for (int i=0;i<4;i++){
#pragma unroll
    for (int r=0;r<4;r++){
      int grow = row0 + (w&1)*64 + i*16 + (ln>>4)*4 + r;
#pragma unroll
      for (int j=0;j<NJ;j++){
        int colb = colb0 + j*16;
        float v = acc[i][j][r];
        if (bias) v += bias[colb];
        if (act){
          float z = 0.7978845608f * v * (1.f + 0.044715f*v*v);
          float e = __expf(2.f*z);
          v = v * (1.f - 1.f/(e + 1.f));
        }
        if (outbf){
          if (qkv){
            int bsel = colb >> 9;
            Cb[(size_t)bsel*bufstride + (size_t)grow*512 + (colb & 511)] = f2b(v);
          } else {
            Cb[(size_t)grow*N + colb] = f2b(v);
          }
        } else {
          Cf[(size_t)grow*N + colb] = v;
        }
      }
    }
  }
}

// ---------------- sample_m2: one wave per (b,l), all 8 heads ----------------
__global__ __launch_bounds__(256) void sample_m2(const unsigned short* __restrict__ q,
    const unsigned short* __restrict__ k, const int* __restrict__ idx, float* __restrict__ m, int L, int u){
  int w = (blockIdx.x*256 + threadIdx.x) >> 6;
  int lane = threadIdx.x & 63;
  int l = w % L; int b = w / L;
  const unsigned short* qrow = q + (size_t)w*DM + lane*8;
  uint4 qq = *(const uint4*)qrow;
  float qv[8];
  qv[0]=b2f((unsigned short)(qq.x&0xffff)); qv[1]=b2f((unsigned short)(qq.x>>16));
  qv[2]=b2f((unsigned short)(qq.y&0xffff)); qv[3]=b2f((unsigned short)(qq.y>>16));
  qv[4]=b2f((unsigned short)(qq.z&0xffff)); qv[5]=b2f((unsigned short)(qq.z>>16));
  qv[6]=b2f((unsigned short)(qq.w&0xffff)); qv[7]=b2f((unsigned short)(qq.w>>16));
  const unsigned short* kb = k + (size_t)b*L*DM + lane*8;
  const int* ip = idx + (size_t)l*u;
  float mx = -1e30f, sum = 0.f;
  for (int s=0; s<u; s++){
    int kp = ip[s];
    uint4 kk = *(const uint4*)(kb + (size_t)kp*DM);
    float p;
    p  = qv[0]*b2f((unsigned short)(kk.x&0xffff)) + qv[1]*b2f((unsigned short)(kk.x>>16));
    p += qv[2]*b2f((unsigned short)(kk.y&0xffff)) + qv[3]*b2f((unsigned short)(kk.y>>16));
    p += qv[4]*b2f((unsigned short)(kk.z&0xffff)) + qv[5]*b2f((unsigned short)(kk.z>>16));
    p += qv[6]*b2f((unsigned short)(kk.w&0xffff)) + qv[7]*b2f((unsigned short)(kk.w>>16));
    p += __shfl_xor(p, 1); p += __shfl_xor(p, 2); p += __shfl_xor(p, 4);
    mx = fmaxf(mx, p); sum += p;
  }
  if ((lane & 7) == 0){
    int hh = lane >> 3;
    m[((size_t)b*8 + hh)*L + l] = mx - sum/(float)u;
  }
}

// ---------------- top-k stage A: per-segment local top-u ----------------
__global__ __launch_bounds__(256) void topkA(const float* __restrict__ m, float* __restrict__ cval,
    int* __restrict__ cidx, int L, int u){
  int bh = blockIdx.x, seg = blockIdx.y;
  int segL = L >> 3;
  int t = threadIdx.x;
  __shared__ float rv[256];
  __shared__ int   ri[256];
  float myv = (t < segL) ? m[(size_t)bh*L + seg*segL + t] : -1e31f;
  int   myi = seg*segL + t;
  for (int it=0; it<u; it++){
    rv[t] = myv; ri[t] = myi;
    __syncthreads();
    for (int s=128; s; s>>=1){
      if (t < s){
        float v2 = rv[t+s]; int i2 = ri[t+s];
        if (v2 > rv[t] || (v2 == rv[t] && i2 < ri[t])){ rv[t] = v2; ri[t] = i2; }
      }
      __syncthreads();
    }
    if (t == 0){
      cval[((size_t)bh*8 + seg)*u + it] = rv[0];
      cidx[((size_t)bh*8 + seg)*u + it] = ri[0];
    }
    __syncthreads();
    if (myi == ri[0]) myv = -1e31f;
    __syncthreads();
  }
}

// ---------------- top-k stage B: merge 8u candidates ----------------
__global__ __launch_bounds__(256) void topkB(const float* __restrict__ cval, const int* __restrict__ cidx,
    int* __restrict__ top, int u){
  int bh = blockIdx.x; int n = 8*u;
  int t = threadIdx.x;
  __shared__ float vals[320];
  __shared__ int   vidx[320];
  __shared__ float rv[256]; __shared__ int rg[256]; __shared__ int rs[256];
  for (int i=t; i<n; i+=256){ vals[i] = cval[(size_t)bh*n + i]; vidx[i] = cidx[(size_t)bh*n + i]; }
  __syncthreads();
  for (int it=0; it<u; it++){
    float bv = -1e31f; int bg = 0x7fffffff, bs = -1;
    for (int i=t; i<n; i+=256){
      float v = vals[i]; int gi = vidx[i];
      if (v > bv || (v == bv && gi < bg)){ bv = v; bg = gi; bs = i; }
    }
    rv[t] = bv; rg[t] = bg; rs[t] = bs;
    __syncthreads();
    for (int s=128; s; s>>=1){
      if (t < s){
        float v2 = rv[t+s]; int g2 = rg[t+s];
        if (v2 > rv[t] || (v2 == rv[t] && g2 < rg[t])){ rv[t]=v2; rg[t]=g2; rs[t]=rs[t+s]; }
      }
      __syncthreads();
    }
    if (t == 0){ top[(size_t)bh*u + it] = rg[0]; vals[rs[0]] = -1e31f; }
    __syncthreads();
  }
}

// ---------------- column mean, two-stage ----------------
#define CMC 32
__global__ __launch_bounds__(256) void colmean1(const float* __restrict__ src, float* __restrict__ part, int L){
  int b = blockIdx.x, ch = blockIdx.y;
  int rpb = L / CMC;
  int t = threadIdx.x;
  const float* p = src + ((size_t)b*L + (size_t)ch*rpb)*DM;
  float s0 = 0.f, s1 = 0.f;
  for (int r=0; r<rpb; r++){ s0 += p[(size_t)r*DM + t]; s1 += p[(size_t)r*DM + t + 256]; }
  float* o = part + ((size_t)b*CMC + ch)*DM;
  o[t] = s0; o[t+256] = s1;
}
__global__ __launch_bounds__(256) void colmean2(const float* __restrict__ part, float* __restrict__ dst, int L){
  int i = blockIdx.x*256 + threadIdx.x;
  int d = i % DM, b = i / DM;
  float s = 0.f;
  for (int c=0; c<CMC; c++) s += part[((size_t)b*CMC + c)*DM + d];
  dst[i] = s / (float)L;
}

// ---------------- tiny fp32 GEMM ----------------
__global__ __launch_bounds__(256) void tiny_gemm(const float* __restrict__ A, const float* __restrict__ W,
    const float* __restrict__ bias, float* __restrict__ C, int N, int K){
  int row = blockIdx.x;
  const float* ar = A + (size_t)row*K;
  __shared__ float as[DM];
  for (int k=threadIdx.x; k<K; k+=256) as[k] = ar[k];
  __syncthreads();
  for (int n = threadIdx.x; n < N; n += 256){
    float acc = bias ? bias[n] : 0.f;
    const float* wr = W + (size_t)n*K;
    for (int k=0; k<K; k++) acc += as[k]*wr[k];
    C[(size_t)row*N + n] = acc;
  }
}

// ---------------- gather q rows for top queries ----------------
__global__ __launch_bounds__(256) void qred_kernel(const unsigned short* __restrict__ q, const int* __restrict__ top,
    float* __restrict__ qred, int L, int u, int n){
  int i = blockIdx.x*256 + threadIdx.x;
  if (i >= n) return;
  int d = i & 63; int rest = i >> 6; int j = rest % u; int bh = rest / u;
  int hh = bh & 7; int b = bh >> 3;
  int pos = top[bh*u + j];
  qred[i] = b2f(q[((size_t)b*L + pos)*DM + hh*DH + d]);
}

// =======================================================================
// flash_attn: fused QK^T -> online softmax -> PV, key-split partials.
// =======================================================================
#define FKT 128
__global__ __launch_bounds__(256) void flash_attn(const float* __restrict__ qred,
    const unsigned short* __restrict__ kbuf, const unsigned short* __restrict__ vbuf,
    float* __restrict__ partM, float* __restrict__ partL, float* __restrict__ partA,
    int L, int u, int KS){
  int ks = blockIdx.x, bh = blockIdx.y; int b = bh >> 3, h = bh & 7;
  int t = threadIdx.x;
  __shared__ float Qs[38*64];
  __shared__ unsigned short Ks[FKT*64];
  __shared__ unsigned short Vs[FKT*64];
  __shared__ float Ss[38*FKT];
  for (int i=t;i<u*64;i+=256) Qs[i] = qred[(size_t)bh*u*64 + i];
  int lane = t & 63, w = t >> 6;
  float rm[10], rl[10], racc[10];
#pragma unroll
  for (int j=0;j<10;j++){ rm[j]=-1e30f; rl[j]=0.f; racc[j]=0.f; }
  int nk = L / KS;
  int kbase = ks*nk;
  int key = t & 127, rh = t >> 7;
  for (int kt = 0; kt < nk; kt += FKT){
    __syncthreads();
    for (int e = t; e < FKT*8; e += 256){
      int k = e >> 3, c = e & 7;
      size_t gidx = ((size_t)(b*L + kbase + kt + k))*DM + h*DH + c*8;
      *(uint4*)((char*)Ks + (size_t)(k*8 + (c ^ (k&7)))*16) = *(const uint4*)(kbuf + gidx);
      *(uint4*)((char*)Vs + (size_t)e*16) = *(const uint4*)(vbuf + gidx);
    }
    __syncthreads();
    for (int r = rh; r < u; r += 2){
      const float4* q4 = (const float4*)(Qs + r*64);
      float acc = 0.f;
#pragma unroll
      for (int c=0;c<8;c++){
        short8 kk = *(const short8*)((char*)Ks + (size_t)(key*8 + (c ^ (key&7)))*16);
        float4 qa = q4[c*2], qb = q4[c*2+1];
        acc += qa.x*b2f((unsigned short)kk[0]) + qa.y*b2f((unsigned short)kk[1])
             + qa.z*b2f((unsigned short)kk[2]) + qa.w*b2f((unsigned short)kk[3]);
        acc += qb.x*b2f((unsigned short)kk[4]) + qb.y*b2f((unsigned short)kk[5])
             + qb.z*b2f((unsigned short)kk[6]) + qb.w*b2f((unsigned short)kk[7]);
      }
      Ss[r*FKT + key] = acc * 0.125f;
    }
    __syncthreads();
    int j = 0;
    for (int r = w; r < u; r += 4, j++){
      float s0 = Ss[r*FKT + lane], s1 = Ss[r*FKT + 64 + lane];
      float mx = fmaxf(s0, s1);
#pragma unroll
      for (int off=32; off; off>>=1) mx = fmaxf(mx, __shfl_xor(mx, off));
      float newm = fmaxf(rm[j], mx);
      float scale = expf(rm[j] - newm);
      float p0 = expf(s0 - newm), p1 = expf(s1 - newm);
      float ps = p0 + p1;
#pragma unroll
      for (int off=32; off; off>>=1) ps += __shfl_xor(ps, off);
      rl[j] = rl[j]*scale + ps;
      rm[j] = newm;
      Ss[r*FKT + lane] = p0; Ss[r*FKT + 64 + lane] = p1;
      float a = racc[j]*scale;
      for (int k=0;k<FKT;k+=4){
        float pa = Ss[r*FKT+k], pb = Ss[r*FKT+k+1], pc = Ss[r*FKT+k+2], pd = Ss[r*FKT+k+3];
        a += pa*b2f(Vs[(k+0)*64+lane]) + pb*b2f(Vs[(k+1)*64+lane])
           + pc*b2f(Vs[(k+2)*64+lane]) + pd*b2f(Vs[(k+3)*64+lane]);
      }
      racc[j] = a;
    }
  }
  int j = 0;
  for (int r = w; r < u; r += 4, j++){
    size_t base = ((size_t)bh*KS + ks)*u + r;
    if (lane == 0){ partM[base] = rm[j]; partL[base] = rl[j]; }
    partA[base*64 + lane] = racc[j];
  }
}

// ---------------- fused merge + sparse residual scatter ----------------
__global__ __launch_bounds__(256) void fms_kernel(const float* __restrict__ partM, const float* __restrict__ partL,
    const float* __restrict__ partA, const float* __restrict__ vmean, const float* __restrict__ wo,
    const int* __restrict__ top, float* __restrict__ h, int L, int u, int KS, int gbase){
  int j = blockIdx.x % u; int bhl = blockIdx.x / u;
  int hh = bhl & 7; int bG = gbase + (bhl >> 3);
  int t = threadIdx.x;
  __shared__ float delta[DH];
  if (t < DH){
    size_t base0 = ((size_t)bhl*KS)*u + j;
    float gm = -1e30f;
    for (int s=0;s<KS;s++) gm = fmaxf(gm, partM[base0 + (size_t)s*u]);
    float lt = 0.f, at = 0.f;
    for (int s=0;s<KS;s++){
      float e = expf(partM[base0 + (size_t)s*u] - gm);
      lt += partL[base0 + (size_t)s*u]*e;
      at += partA[(base0 + (size_t)s*u)*64 + t]*e;
    }
    delta[t] = at/lt - vmean[(size_t)bG*DM + hh*DH + t];
  }
  __syncthreads();
  int pos = top[(size_t)bhl*u + j];
  float* hrow = h + ((size_t)bG*L + pos)*DM;
  const float* wbase = wo + hh*DH;
  for (int n = t; n < DM; n += 256){
    float acc = 0.f;
    const float* wr = wbase + (size_t)n*DM;
#pragma unroll
    for (int dd=0; dd<DH; dd++) acc += delta[dd] * wr[dd];
    atomicAdd(&hrow[n], acc);
  }
}

// ---------------- LayerNorm D=512; optional +cw[b], +Yadd; out fp32/bf16 ----------------
__global__ __launch_bounds__(256) void ln_kernel(const float* __restrict__ X, const void* __restrict__ Yadd,
    int yb, const float* __restrict__ g, const float* __restrict__ bta, void* __restrict__ Out, int ob,
    const float* __restrict__ cwv, int Lrow, int row0g){
  size_t row = blockIdx.x;
  const float* xr = X + row*DM;
  int t = threadIdx.x;
  float v0 = xr[t], v1 = xr[t+256];
  if (cwv){
    int b = (int)((row0g + (int)row) / Lrow);
    v0 += cwv[b*DM + t]; v1 += cwv[b*DM + t+256];
  }
  if (Yadd){
    if (yb){ const unsigned short* yr = (const unsigned short*)Yadd + row*DM; v0 += b2f(yr[t]); v1 += b2f(yr[t+256]); }
    else   { const float* yr = (const float*)Yadd + row*DM; v0 += yr[t]; v1 += yr[t+256]; }
  }
  float s = v0+v1, q = v0*v0+v1*v1;
#pragma unroll
  for (int off=32; off; off>>=1){ s += __shfl_xor(s,off); q += __shfl_xor(q,off); }
  __shared__ float ss[4], qq[4];
  int w = t >> 6;
  if ((t & 63) == 0){ ss[w] = s; qq[w] = q; }
  __syncthreads();
  s = ss[0]+ss[1]+ss[2]+ss[3]; q = qq[0]+qq[1]+qq[2]+qq[3];
  float mu  = s * (1.0f/DM);
  float var = q * (1.0f/DM) - mu*mu;
  float r = rsqrtf(var + 1e-5f);
  float o0 = (v0 - mu)*r*g[t]     + bta[t];
  float o1 = (v1 - mu)*r*g[t+256] + bta[t+256];
  if (ob){
    unsigned short* Ob = (unsigned short*)Out;
    Ob[row*DM + t] = f2b(o0); Ob[row*DM + t+256] = f2b(o1);
  } else {
    float* Of = (float*)Out;
    Of[row*DM + t] = o0; Of[row*DM + t+256] = o1;
  }
}

// ---------------- BN partial sums over bf16 conv output ----------------
__global__ __launch_bounds__(256) void bnstat1(const unsigned short* __restrict__ C, float* __restrict__ partS,
                                               float* __restrict__ partQ, int rpb){
  int chb = blockIdx.x;
  int mb  = blockIdx.y;
  int g = threadIdx.x >> 6, c = threadIdx.x & 63;
  int ch = chb*64 + c;
  float s = 0.f, q = 0.f;
  int r0 = mb * rpb;
  for (int r = r0 + g; r < r0 + rpb; r += 4){
    float v = b2f(C[(size_t)r*DM + ch]); s += v; q += v*v;
  }
  __shared__ float ls[4][64], lq[4][64];
  ls[g][c] = s; lq[g][c] = q;
  __syncthreads();
  if (g == 0){
    s = ls[0][c]+ls[1][c]+ls[2][c]+ls[3][c];
    q = lq[0][c]+lq[1][c]+lq[2][c]+lq[3][c];
    partS[(size_t)mb*DM + ch] = s;
    partQ[(size_t)mb*DM + ch] = q;
  }
}
__global__ __launch_bounds__(256) void bnstat2(const float* __restrict__ partS, const float* __restrict__ partQ,
                                               float* __restrict__ stats, int NB, int M){
  int ch = blockIdx.x*256 + threadIdx.x;
  if (ch >= DM) return;
  float s = 0.f, q = 0.f;
  for (int mb=0; mb<NB; mb++){
    s += partS[(size_t)mb*DM + ch];
    q += partQ[(size_t)mb*DM + ch];
  }
  float mu = s / (float)M;
  stats[ch] = mu;
  stats[DM + ch] = q / (float)M - mu*mu;
}

// ---------------- BN + ELU + maxpool(3,2) ----------------
__global__ __launch_bounds__(256) void bnpool(const unsigned short* __restrict__ C, const float* __restrict__ stats,
    const float* __restrict__ g, const float* __restrict__ bta, float* __restrict__ Out,
    int L, int Lo){
  size_t i = (size_t)blockIdx.x*256 + threadIdx.x;
  int ch = (int)(i % DM);
  size_t r = i / DM;
  int lo = (int)(r % Lo);
  int b  = (int)(r / Lo);
  float mu = stats[ch];
  float rstd = rsqrtf(stats[DM+ch] + 1e-5f);
  float gg = g[ch], bb = bta[ch];
  float best = -1e30f;
#pragma unroll
  for (int t=-1; t<=1; t++){
    int li = 2*lo + t;
    if (li >= 0 && li < L){
      float v = (b2f(C[((size_t)b*L + li)*DM + ch]) - mu)*rstd*gg + bb;
      v = v > 0.f ? v : expm1f(v);
      best = fmaxf(best, v);
    }
  }
  Out[((size_t)b*Lo + lo)*DM + ch] = best;
}

// ---------------- final: LN(last row) @ proj^T + proj_b + skip ----------------
__global__ __launch_bounds__(128) void final_kernel(const float* __restrict__ h, const float* __restrict__ x,
    const float* __restrict__ fg, const float* __restrict__ fb, const float* __restrict__ pw,
    const float* __restrict__ pb, const float* __restrict__ sw, const float* __restrict__ sb,
    float* __restrict__ out, int Lf, int L0){
  int b = blockIdx.x;
  const float* row = h + ((size_t)b*Lf + (Lf-1))*DM;
  __shared__ float xn[DM];
  __shared__ float rs[2], rq[2];
  int t = threadIdx.x;
  float v[4]; float s = 0.f, q = 0.f;
#pragma unroll
  for (int i=0;i<4;i++){ v[i] = row[t + i*128]; s += v[i]; q += v[i]*v[i]; }
#pragma unroll
  for (int off=32; off; off>>=1){ s += __shfl_xor(s,off); q += __shfl_xor(q,off); }
  if ((t & 63) == 0){ rs[t>>6] = s; rq[t>>6] = q; }
  __syncthreads();
  s = rs[0]+rs[1]; q = rq[0]+rq[1];
  float mu = s*(1.0f/DM), var = q*(1.0f/DM) - mu*mu;
  float r = rsqrtf(var + 1e-5f);
#pragma unroll
  for (int i=0;i<4;i++){ int d = t + i*128; xn[d] = (v[i]-mu)*r*fg[d] + fb[d]; }
  __syncthreads();
  if (t < 96){
    float acc = pb[t] + sb[t];
    const float* xr = x + ((size_t)b*L0 + (L0-1))*7;
#pragma unroll
    for (int c=0;c<7;c++) acc += xr[c]*sw[t*7+c];
    for (int d=0; d<DM; d++) acc += xn[d]*pw[(size_t)t*DM + d];
    out[b*96 + t] = acc;
  }
}

// =======================================================================
extern "C" void kernel_launch(void* const* d_in, const int* in_sizes, int n_in,
                              void* d_out, int out_size, void* d_ws, size_t ws_size,
                              hipStream_t stream){
  const float* x    = (const float*)d_in[0];
  const float* skw  = (const float*)d_in[1];
  const float* skb  = (const float*)d_in[2];
  const float* tcw  = (const float*)d_in[3];
  const float* wq   = (const float*)d_in[4];
  const float* bq   = (const float*)d_in[5];
  const float* wk   = (const float*)d_in[6];
  const float* bk   = (const float*)d_in[7];
  const float* wv   = (const float*)d_in[8];
  const float* bv   = (const float*)d_in[9];
  const float* wo   = (const float*)d_in[10];
  const float* bo   = (const float*)d_in[11];
  const float* w1   = (const float*)d_in[12];
  const float* b1   = (const float*)d_in[13];
  const float* w2   = (const float*)d_in[14];
  const float* b2   = (const float*)d_in[15];
  const float* ln1g = (const float*)d_in[16];
  const float* ln1b = (const float*)d_in[17];
  const float* ln2g = (const float*)d_in[18];
  const float* ln2b = (const float*)d_in[19];
  const float* dcw  = (const float*)d_in[20];
  const float* dcb  = (const float*)d_in[21];
  const float* bng  = (const float*)d_in[22];
  const float* bnb  = (const float*)d_in[23];
  const float* flg  = (const float*)d_in[24];
  const float* flb  = (const float*)d_in[25];
  const float* pw   = (const float*)d_in[26];
  const float* pb   = (const float*)d_in[27];

  const int B = 32, L0 = 2048, DFF = 2048;
  const int RG = 16384;
  const int RF = 8192;
  char* ws = (char*)d_ws;
  const size_t SZH  = (size_t)B*L0*DM*sizeof(float);
  const size_t SLOT = (size_t)RG*DM*sizeof(unsigned short);

  const size_t WBSZ = (size_t)(3*DM*DM + 2*DFF*DM + 3*DM*DM)*2;
  const size_t NCAND = (size_t)256*8*40;
  size_t small_bytes = (size_t)L0*40*4
                     + (size_t)RG*8*4
                     + (size_t)B*8*40*4
                     + (size_t)32*8*40*64*4
                     + 3*(size_t)B*DM*4
                     + 2*(size_t)128*DM*4
                     + (size_t)2*DM*4
                     + (size_t)1536*4
                     + (size_t)B*CMC*DM*4
                     + (size_t)L0*DM*4
                     + (size_t)21*DM*4
                     + 2*NCAND*4;
  if (ws_size < SZH + 4*SLOT + WBSZ + small_bytes) return;

  float*          h   = (float*)(ws);
  unsigned short* P0  = (unsigned short*)(ws + SZH);
  unsigned short* P1  = (unsigned short*)(ws + SZH + SLOT);
  unsigned short* P2  = (unsigned short*)(ws + SZH + 2*SLOT);
  unsigned short* P3  = (unsigned short*)(ws + SZH + 3*SLOT);
  unsigned short* wb  = (unsigned short*)(ws + SZH + 4*SLOT);
  unsigned short* wqb = wb;
  unsigned short* w1b = wqb + (size_t)3*DM*DM;
  unsigned short* w2b = w1b + (size_t)DFF*DM;
  unsigned short* wtapK= w2b + (size_t)DM*DFF;
  char* sm = ws + SZH + 4*SLOT + WBSZ;
  int*   idx_buf  = (int*)sm;
  float* m_buf    = (float*)(sm + (size_t)L0*40*4);
  int*   top_all  = (int*)((char*)m_buf + (size_t)RG*8*4);
  float* qred_loc = (float*)((char*)top_all + (size_t)B*8*40*4);
  float* hm       = qred_loc + (size_t)32*8*40*64;
  float* vmean    = hm + (size_t)B*DM;
  float* cw       = vmean + (size_t)B*DM;
  float* partS    = cw + (size_t)B*DM;
  float* partQ    = partS + (size_t)128*DM;
  float* stats    = partQ + (size_t)128*DM;
  float* bqkv     = stats + (size_t)2*DM;
  float* partC    = bqkv + (size_t)1536;
  float* pe_buf   = partC + (size_t)B*CMC*DM;
  float* tcwT     = pe_buf + (size_t)L0*DM;
  float* cvalB    = tcwT + (size_t)21*DM;                 // NCAND
  int*   cidxB    = (int*)(cvalB + NCAND);                // NCAND

  // flash partials live in P0 (free during attention)
  float* fpM = (float*)P0;                       // (G*8)*KS*u <= 64*4*40
  float* fpL = fpM + (size_t)64*8*40;
  float* fpA = fpL + (size_t)64*8*40;

  auto conv_b = [&](const float* src, unsigned short* dst, size_t n){
    f2b_vec<<<(int)((n/4 + 255)/256), 256, 0, stream>>>(src, dst, (int)(n/4));
  };

  pe_kernel<<<(int)(((size_t)L0*DM)/256), 256, 0, stream>>>(pe_buf, L0);
  packtcw<<<(21*DM + 255)/256, 256, 0, stream>>>(tcw, tcwT);
  embed2<<<B*L0, 256, 0, stream>>>(x, tcwT, pe_buf, h, L0);

  int L = L0;
  for (int layer = 0; layer < 3; layer++){
    int M = B * L;
    int u = (int)(5.0 * log((double)L + 1.0));   // 38 / 34 / 31
    int G = RG / L;
    int nG = M / RG;
    int KS = L / 512;                            // 4 / 2 / 1 key-splits
    const float* wv_i = wv + (size_t)layer*DM*DM;  const float* bv_i = bv + (size_t)layer*DM;
    const float* wo_i = wo + (size_t)layer*DM*DM;  const float* bo_i = bo + (size_t)layer*DM;
    const float* b1_i = b1 + (size_t)layer*DFF;
    const float* b2_i = b2 + (size_t)layer*DM;

    conv_b(wq + (size_t)layer*DM*DM, wqb,                    (size_t)DM*DM);
    conv_b(wk + (size_t)layer*DM*DM, wqb + (size_t)DM*DM,    (size_t)DM*DM);
    conv_b(wv_i,                     wqb + (size_t)2*DM*DM,  (size_t)DM*DM);
    conv_b(w1 + (size_t)layer*DFF*DM, w1b, (size_t)DFF*DM);
    conv_b(w2 + (size_t)layer*DM*DFF, w2b, (size_t)DM*DFF);
    catb_kernel<<<6, 256, 0, stream>>>(bq + (size_t)layer*DM, bk + (size_t)layer*DM, bv_i, bqkv);
    if (layer < 2)
      packconv<<<(3*DM*DM + 255)/256, 256, 0, stream>>>(dcw + (size_t)layer*DM*DM*3, wtapK);

    unsigned ka = 0u, kb2 = (unsigned)layer;
    tf2x32(0u, 42u, ka, kb2);
    unsigned a0 = 0u, a1 = 2u;  tf2x32(ka, kb2, a0, a1);
    unsigned c0 = 1u, c1 = 3u;  tf2x32(ka, kb2, c0, c1);
    int S2 = L * u / 2;
    idx_kernel<<<(S2 + 255)/256, 256, 0, stream>>>(idx_buf, a1, c1, S2, L-1);

    // vmean/cw (exact fp32 identity), needed by fms + LN folding
    colmean1<<<dim3(B, CMC), 256, 0, stream>>>(h, partC, L);
    colmean2<<<B*DM/256, 256, 0, stream>>>(partC, hm, L);
    tiny_gemm<<<B, 256, 0, stream>>>(hm, wv_i, bv_i, vmean, DM, DM);
    tiny_gemm<<<B, 256, 0, stream>>>(vmean, wo_i, bo_i, cw, DM, DM);

    for (int g = 0; g < nG; g++){
      const float* hg = h + (size_t)g*RG*DM;
      bgemm2<128,1><<<dim3(12, RG/128), 256, 0, stream>>>(hg, wqb, bqkv, P1,
          1536, 512, L, 0, 0, 1, 1, (size_t)RG*DM, 1);
      sample_m2<<<RG/4, 256, 0, stream>>>(P1, P2, idx_buf, m_buf, L, u);
      int* top_g = top_all + (size_t)g*G*8*u;
      topkA<<<dim3(G*8, 8), 256, 0, stream>>>(m_buf, cvalB, cidxB, L, u);
      topkB<<<G*8, 256, 0, stream>>>(cvalB, cidxB, top_g, u);
      int nqr = G*8*u*DH;
      qred_kernel<<<(nqr + 255)/256, 256, 0, stream>>>(P1, top_g, qred_loc, L, u, nqr);

      flash_attn<<<dim3(KS, G*8), 256, 0, stream>>>(qred_loc, P2, P3, fpM, fpL, fpA, L, u, KS);
      fms_kernel<<<G*8*u, 256, 0, stream>>>(fpM, fpL, fpA, vmean, wo_i, top_g, h, L, u, KS, g*G);
    }

    // FFN: LN1(+cw) -> bf16 ybuf -> FFN1(GELU) -> FFN2 -> LN2(+cw) in-place on h
    unsigned short* ybuf = P0;
    unsigned short* mid  = P1;
    unsigned short* y2b  = P0 + (size_t)RF*DM;
    const float* l1g = ln1g + (size_t)layer*DM; const float* l1b = ln1b + (size_t)layer*DM;
    const float* l2g = ln2g + (size_t)layer*DM; const float* l2b = ln2b + (size_t)layer*DM;
    for (int r0 = 0; r0 < M; r0 += RF){
      ln_kernel<<<RF, 256, 0, stream>>>(h + (size_t)r0*DM, nullptr, 0, l1g, l1b, ybuf, 1, cw, L, r0);
      bgemm2<128,0><<<dim3(16, RF/128), 256, 0, stream>>>(ybuf, w1b, b1_i, mid,
          2048, 512, L, 0, 1, 1, 0, 0, 1);
      bgemm2<64,0><<<dim3(8, RF/128), 256, 0, stream>>>(mid, w2b, b2_i, y2b,
          512, 2048, L, 0, 0, 1, 0, 0, 1);
      ln_kernel<<<RF, 256, 0, stream>>>(h + (size_t)r0*DM, y2b, 1, l2g, l2b, h + (size_t)r0*DM, 0, cw, L, r0);
    }

    if (layer < 2){
      const float* db = dcb + (size_t)layer*DM;
      unsigned short* convb = P0;
      bgemm2<64,1><<<dim3(8, M/128), 256, 0, stream>>>(h, wtapK, db, convb,
          512, 1536, L, 1, 0, 1, 0, 0, 1);
      bnstat1<<<dim3(8, 128), 256, 0, stream>>>(convb, partS, partQ, M/128);
      bnstat2<<<2, 256, 0, stream>>>(partS, partQ, stats, 128, M);
      int Lo = L/2;
      bnpool<<<(int)(((size_t)B*Lo*DM)/256), 256, 0, stream>>>(convb, stats,
          bng + (size_t)layer*DM, bnb + (size_t)layer*DM, h, L, Lo);
      L = Lo;
    }
  }

  final_kernel<<<B, 128, 0, stream>>>(h, x, flg, flb, pw, pb, skw, skb, (float*)d_out, L, L0);
}

// Round 13
// 5607.033 us; speedup vs baseline: 1.0652x; 1.0000x over previous
//
#include <hip/hip_runtime.h>
#include <cmath>

#define DM 512
#define DH 64

typedef __attribute__((ext_vector_type(8))) short short8;
typedef __attribute__((ext_vector_type(4))) float float4v;

__device__ inline float b2f(unsigned short u){
  union{unsigned int i; float f;} z; z.i = ((unsigned)u)<<16; return z.f;
}
__device__ inline unsigned short f2b(float f){
  unsigned int x = __float_as_uint(f);
  return (unsigned short)((x + 0x7fffu + ((x>>16)&1u)) >> 16);   // RNE
}

#define GLL(gp, lp) __builtin_amdgcn_global_load_lds((const __attribute__((address_space(1))) void*)(gp), \
    (__attribute__((address_space(3))) void*)(lp), 16, 0, 0)

// ---------------- Threefry-2x32-20 (matches jax.random) ----------------
__host__ __device__ inline void tf2x32(unsigned k0, unsigned k1, unsigned& x0, unsigned& x1){
  const unsigned ks0=k0, ks1=k1, ks2=k0^k1^0x1BD11BDAu;
  x0 += ks0; x1 += ks1;
#define TF_ROT(r) { x0 += x1; x1 = (x1<<(r))|(x1>>(32-(r))); x1 ^= x0; }
  TF_ROT(13) TF_ROT(15) TF_ROT(26) TF_ROT(6)
  x0 += ks1; x1 += ks2 + 1u;
  TF_ROT(17) TF_ROT(29) TF_ROT(16) TF_ROT(24)
  x0 += ks2; x1 += ks0 + 2u;
  TF_ROT(13) TF_ROT(15) TF_ROT(26) TF_ROT(6)
  x0 += ks0; x1 += ks1 + 3u;
  TF_ROT(17) TF_ROT(29) TF_ROT(16) TF_ROT(24)
  x0 += ks1; x1 += ks2 + 4u;
  TF_ROT(13) TF_ROT(15) TF_ROT(26) TF_ROT(6)
  x0 += ks2; x1 += ks0 + 5u;
#undef TF_ROT
}

__global__ __launch_bounds__(256) void idx_kernel(int* __restrict__ idx, unsigned k2a, unsigned k2b,
                                                  int S2, int Lmask){
  int j = blockIdx.x*256 + threadIdx.x;
  if (j >= S2) return;
  unsigned x0 = (unsigned)j, x1 = (unsigned)(S2 + j);
  tf2x32(k2a, k2b, x0, x1);
  idx[j]      = (int)(x0 & (unsigned)Lmask);
  idx[S2 + j] = (int)(x1 & (unsigned)Lmask);
}

// ---------------- positional-embedding table ----------------
__global__ __launch_bounds__(256) void pe_kernel(float* __restrict__ pe, int L){
  int i = blockIdx.x*256 + threadIdx.x;
  int d = i % DM, l = i / DM;
  const float scale = -0.017988946f;  // -ln(10000)/512
  float freq = expf((float)(d & ~1) * scale);
  float ang  = (float)l * freq;
  pe[i] = (d & 1) ? cosf(ang) : sinf(ang);
}

// ---------------- transpose token-conv weights ----------------
__global__ __launch_bounds__(256) void packtcw(const float* __restrict__ tcw, float* __restrict__ tcwT){
  int i = blockIdx.x*256 + threadIdx.x;
  if (i >= 21*DM) return;
  int j = i / DM, d = i % DM;
  tcwT[(size_t)j*DM + d] = tcw[(size_t)d*21 + (j%7)*3 + (j/7)];
}

// ---------------- token embed ----------------
__global__ __launch_bounds__(256) void embed2(const float* __restrict__ x, const float* __restrict__ tcwT,
                                              const float* __restrict__ pe, float* __restrict__ h, int L){
  int row = blockIdx.x; int l = row % L, b = row / L;
  __shared__ float xs[21];
  int t = threadIdx.x;
  if (t < 21){
    int c = t % 7, kk = t / 7;
    int ls = l + kk - 1; ls = (ls < 0) ? ls + L : (ls >= L ? ls - L : ls);
    xs[t] = x[((size_t)b*L + ls)*7 + c];
  }
  __syncthreads();
  for (int d = t; d < DM; d += 256){
    float acc = 0.f;
#pragma unroll
    for (int j=0;j<21;j++) acc += xs[j]*tcwT[j*DM + d];
    h[(size_t)row*DM + d] = acc + pe[(size_t)l*DM + d];
  }
}

// ---------------- fp32 -> bf16 conversion (weights) ----------------
__global__ __launch_bounds__(256) void f2b_vec(const float* __restrict__ src, unsigned short* __restrict__ dst, int n4){
  int i = blockIdx.x*256 + threadIdx.x;
  if (i >= n4) return;
  float4 v = ((const float4*)src)[i];
  ushort4 o; o.x = f2b(v.x); o.y = f2b(v.y); o.z = f2b(v.z); o.w = f2b(v.w);
  ((ushort4*)dst)[i] = o;
}

// ---------------- pack conv weights along K ----------------
__global__ __launch_bounds__(256) void packconv(const float* __restrict__ dcw, unsigned short* __restrict__ wtapK){
  int i = blockIdx.x*256 + threadIdx.x;
  if (i >= 3*DM*DM) return;
  int n = i / (3*DM); int rem = i % (3*DM); int tap = rem / DM; int c = rem % DM;
  wtapK[(size_t)n*(3*DM) + tap*DM + c] = f2b(dcw[((size_t)n*DM + c)*3 + tap]);
}

// ---------------- concat qkv bias ----------------
__global__ __launch_bounds__(256) void catb_kernel(const float* __restrict__ a, const float* __restrict__ b,
    const float* __restrict__ c, float* __restrict__ o){
  int i = blockIdx.x*256 + threadIdx.x;
  if (i >= 1536) return;
  o[i] = (i < 512) ? a[i] : (i < 1024 ? b[i-512] : c[i-1024]);
}

// =======================================================================
// bgemm2: bf16 MFMA GEMM, 128xTN, BK=64, single-buffered staging.
// A32: fp32 A, VGPR convert. swz: XCD-aware L2-locality remap (CHv=16).
// convmode: 3-tap circular K=1536. qkv: route 512-col groups to
// bufstride-spaced buffers. act: tanh GELU.
// =======================================================================
template<int TN, int A32>
__global__ __launch_bounds__(256) void bgemm2(const void* __restrict__ Ain,
    const unsigned short* __restrict__ Wb, const float* __restrict__ bias, void* __restrict__ C,
    int N, int K, int L, int convmode, int act, int outbf, int qkv, size_t bufstride, int swz){
  constexpr int NJ = TN/32;
  constexpr int BR = TN/32;
  __shared__ unsigned short As[128*64];
  __shared__ unsigned short Bs[TN*64];
  int tid = threadIdx.x;
  int w = tid >> 6, ln = tid & 63;

  int bx = blockIdx.x, by = blockIdx.y;
  if (swz){
    int XT = gridDim.x, YT = gridDim.y;
    int lid = by*XT + bx;
    int xcd = lid & 7, s = lid >> 3;
    int ych = YT >> 3;
    int CHv = ych < 16 ? ych : 16;
    int yloc = s % CHv;
    int t2 = s / CHv;
    int xx = t2 % XT;
    int chunk = t2 / XT;
    by = xcd*ych + chunk*CHv + yloc;
    bx = xx;
  }
  int row0 = by*128, col0 = bx*TN;
  int KA = convmode ? 512 : K;

  long aBase[4], dPrev[4], dNext[4]; int aCol[4];
#pragma unroll
  for (int g=0; g<4; g++){
    int ch = g*256 + tid;
    int r = ch >> 3, c = ch & 7;
    int gc = c ^ (r & 7);
    int gr = row0 + r;
    aCol[g] = gc*8;
    aBase[g] = (long)gr * KA;
    if (convmode){
      int l = gr % L;
      dPrev[g] = (l==0)   ? (long)(L-1)*KA : -(long)KA;
      dNext[g] = (l==L-1) ? -(long)(L-1)*KA : (long)KA;
    } else { dPrev[g]=0; dNext[g]=0; }
  }
  long bBase[BR];
#pragma unroll
  for (int g=0; g<BR; g++){
    int ch = g*256 + tid;
    int r = ch >> 3, c = ch & 7;
    int gc = c ^ (r & 7);
    bBase[g] = (long)(col0 + r)*K + gc*8;
  }
  int raBase[4], rbBase[NJ];
#pragma unroll
  for (int i=0;i<4;i++)  raBase[i] = ((w&1)*64 + i*16 + (ln&15))*8;
#pragma unroll
  for (int j=0;j<NJ;j++) rbBase[j] = ((w>>1)*(TN/2) + j*16 + (ln&15))*8;

  float4v acc[4][NJ] = {};
  int nIter = K/64;
  const unsigned short* A16 = (const unsigned short*)Ain;
  const float* Af = (const float*)Ain;

  for (int it=0; it<nIter; it++){
    int k0 = it*64;
    int kk = convmode ? (k0 & 511) : k0;
    int seg = convmode ? (k0 >> 9) : 1;
    if (A32){
#pragma unroll
      for (int g=0; g<4; g++){
        long d = convmode ? ((seg==0) ? dPrev[g] : (seg==2 ? dNext[g] : 0)) : 0;
        const float* src = Af + aBase[g] + d + kk + aCol[g];
        float4 v0 = *(const float4*)src;
        float4 v1 = *(const float4*)(src+4);
        short8 pk;
        pk[0]=(short)f2b(v0.x); pk[1]=(short)f2b(v0.y); pk[2]=(short)f2b(v0.z); pk[3]=(short)f2b(v0.w);
        pk[4]=(short)f2b(v1.x); pk[5]=(short)f2b(v1.y); pk[6]=(short)f2b(v1.z); pk[7]=(short)f2b(v1.w);
        *(short8*)((char*)As + g*4096 + tid*16) = pk;
      }
    } else {
#pragma unroll
      for (int g=0; g<4; g++){
        long d = convmode ? ((seg==0) ? dPrev[g] : (seg==2 ? dNext[g] : 0)) : 0;
        GLL(A16 + aBase[g] + d + kk + aCol[g], (char*)As + g*4096 + w*1024);
      }
    }
#pragma unroll
    for (int g=0; g<BR; g++)
      GLL(Wb + bBase[g] + k0, (char*)Bs + g*4096 + w*1024);
    __syncthreads();
    const char* ab = (const char*)As;
    const char* bb = (const char*)Bs;
#pragma unroll
    for (int s=0;s<2;s++){
      int xs = (s*4 + (ln>>4)) ^ (ln&7);
      short8 af[4], bf[NJ];
#pragma unroll
      for (int i=0;i<4;i++)  af[i] = *(const short8*)(ab + (raBase[i] + xs)*16);
#pragma unroll
      for (int j=0;j<NJ;j++) bf[j] = *(const short8*)(bb + (rbBase[j] + xs)*16);
#pragma unroll
      for (int i=0;i<4;i++)
#pragma unroll
        for (int j=0;j<NJ;j++)
          acc[i][j] = __builtin_amdgcn_mfma_f32_16x16x32_bf16(af[i], bf[j], acc[i][j], 0, 0, 0);
    }
    __syncthreads();
  }

  float* Cf = (float*)C;
  unsigned short* Cb = (unsigned short*)C;
  int colb0 = col0 + (w>>1)*(TN/2) + (ln & 15);
#pragma unroll
  for (int i=0;i<4;i++){
#pragma unroll
    for (int r=0;r<4;r++){
      int grow = row0 + (w&1)*64 + i*16 + (ln>>4)*4 + r;
#pragma unroll
      for (int j=0;j<NJ;j++){
        int colb = colb0 + j*16;
        float v = acc[i][j][r];
        if (bias) v += bias[colb];
        if (act){
          float z = 0.7978845608f * v * (1.f + 0.044715f*v*v);
          float e = __expf(2.f*z);
          v = v * (1.f - 1.f/(e + 1.f));
        }
        if (outbf){
          if (qkv){
            int bsel = colb >> 9;
            Cb[(size_t)bsel*bufstride + (size_t)grow*512 + (colb & 511)] = f2b(v);
          } else {
            Cb[(size_t)grow*N + colb] = f2b(v);
          }
        } else {
          Cf[(size_t)grow*N + colb] = v;
        }
      }
    }
  }
}

// ---------------- sample_m2: one wave per (b,l), all 8 heads ----------------
__global__ __launch_bounds__(256) void sample_m2(const unsigned short* __restrict__ q,
    const unsigned short* __restrict__ k, const int* __restrict__ idx, float* __restrict__ m, int L, int u){
  int w = (blockIdx.x*256 + threadIdx.x) >> 6;
  int lane = threadIdx.x & 63;
  int l = w % L; int b = w / L;
  const unsigned short* qrow = q + (size_t)w*DM + lane*8;
  uint4 qq = *(const uint4*)qrow;
  float qv[8];
  qv[0]=b2f((unsigned short)(qq.x&0xffff)); qv[1]=b2f((unsigned short)(qq.x>>16));
  qv[2]=b2f((unsigned short)(qq.y&0xffff)); qv[3]=b2f((unsigned short)(qq.y>>16));
  qv[4]=b2f((unsigned short)(qq.z&0xffff)); qv[5]=b2f((unsigned short)(qq.z>>16));
  qv[6]=b2f((unsigned short)(qq.w&0xffff)); qv[7]=b2f((unsigned short)(qq.w>>16));
  const unsigned short* kb = k + (size_t)b*L*DM + lane*8;
  const int* ip = idx + (size_t)l*u;
  float mx = -1e30f, sum = 0.f;
  for (int s=0; s<u; s++){
    int kp = ip[s];
    uint4 kk = *(const uint4*)(kb + (size_t)kp*DM);
    float p;
    p  = qv[0]*b2f((unsigned short)(kk.x&0xffff)) + qv[1]*b2f((unsigned short)(kk.x>>16));
    p += qv[2]*b2f((unsigned short)(kk.y&0xffff)) + qv[3]*b2f((unsigned short)(kk.y>>16));
    p += qv[4]*b2f((unsigned short)(kk.z&0xffff)) + qv[5]*b2f((unsigned short)(kk.z>>16));
    p += qv[6]*b2f((unsigned short)(kk.w&0xffff)) + qv[7]*b2f((unsigned short)(kk.w>>16));
    p += __shfl_xor(p, 1); p += __shfl_xor(p, 2); p += __shfl_xor(p, 4);
    mx = fmaxf(mx, p); sum += p;
  }
  if ((lane & 7) == 0){
    int hh = lane >> 3;
    m[((size_t)b*8 + hh)*L + l] = mx - sum/(float)u;
  }
}

// ---------------- top-k stage A: per-segment local top-u ----------------
__global__ __launch_bounds__(256) void topkA(const float* __restrict__ m, float* __restrict__ cval,
    int* __restrict__ cidx, int L, int u){
  int bh = blockIdx.x, seg = blockIdx.y;
  int segL = L >> 3;
  int t = threadIdx.x;
  __shared__ float rv[256];
  __shared__ int   ri[256];
  float myv = (t < segL) ? m[(size_t)bh*L + seg*segL + t] : -1e31f;
  int   myi = seg*segL + t;
  for (int it=0; it<u; it++){
    rv[t] = myv; ri[t] = myi;
    __syncthreads();
    for (int s=128; s; s>>=1){
      if (t < s){
        float v2 = rv[t+s]; int i2 = ri[t+s];
        if (v2 > rv[t] || (v2 == rv[t] && i2 < ri[t])){ rv[t] = v2; ri[t] = i2; }
      }
      __syncthreads();
    }
    if (t == 0){
      cval[((size_t)bh*8 + seg)*u + it] = rv[0];
      cidx[((size_t)bh*8 + seg)*u + it] = ri[0];
    }
    __syncthreads();
    if (myi == ri[0]) myv = -1e31f;
    __syncthreads();
  }
}

// ---------------- top-k stage B: merge 8u candidates ----------------
__global__ __launch_bounds__(256) void topkB(const float* __restrict__ cval, const int* __restrict__ cidx,
    int* __restrict__ top, int u){
  int bh = blockIdx.x; int n = 8*u;
  int t = threadIdx.x;
  __shared__ float vals[320];
  __shared__ int   vidx[320];
  __shared__ float rv[256]; __shared__ int rg[256]; __shared__ int rs[256];
  for (int i=t; i<n; i+=256){ vals[i] = cval[(size_t)bh*n + i]; vidx[i] = cidx[(size_t)bh*n + i]; }
  __syncthreads();
  for (int it=0; it<u; it++){
    float bv = -1e31f; int bg = 0x7fffffff, bs = -1;
    for (int i=t; i<n; i+=256){
      float v = vals[i]; int gi = vidx[i];
      if (v > bv || (v == bv && gi < bg)){ bv = v; bg = gi; bs = i; }
    }
    rv[t] = bv; rg[t] = bg; rs[t] = bs;
    __syncthreads();
    for (int s=128; s; s>>=1){
      if (t < s){
        float v2 = rv[t+s]; int g2 = rg[t+s];
        if (v2 > rv[t] || (v2 == rv[t] && g2 < rg[t])){ rv[t]=v2; rg[t]=g2; rs[t]=rs[t+s]; }
      }
      __syncthreads();
    }
    if (t == 0){ top[(size_t)bh*u + it] = rg[0]; vals[rs[0]] = -1e31f; }
    __syncthreads();
  }
}

// ---------------- column mean, two-stage ----------------
#define CMC 32
__global__ __launch_bounds__(256) void colmean1(const float* __restrict__ src, float* __restrict__ part, int L){
  int b = blockIdx.x, ch = blockIdx.y;
  int rpb = L / CMC;
  int t = threadIdx.x;
  const float* p = src + ((size_t)b*L + (size_t)ch*rpb)*DM;
  float s0 = 0.f, s1 = 0.f;
  for (int r=0; r<rpb; r++){ s0 += p[(size_t)r*DM + t]; s1 += p[(size_t)r*DM + t + 256]; }
  float* o = part + ((size_t)b*CMC + ch)*DM;
  o[t] = s0; o[t+256] = s1;
}
__global__ __launch_bounds__(256) void colmean2(const float* __restrict__ part, float* __restrict__ dst, int L){
  int i = blockIdx.x*256 + threadIdx.x;
  int d = i % DM, b = i / DM;
  float s = 0.f;
  for (int c=0; c<CMC; c++) s += part[((size_t)b*CMC + c)*DM + d];
  dst[i] = s / (float)L;
}

// ---------------- tiny fp32 GEMM ----------------
__global__ __launch_bounds__(256) void tiny_gemm(const float* __restrict__ A, const float* __restrict__ W,
    const float* __restrict__ bias, float* __restrict__ C, int N, int K){
  int row = blockIdx.x;
  const float* ar = A + (size_t)row*K;
  __shared__ float as[DM];
  for (int k=threadIdx.x; k<K; k+=256) as[k] = ar[k];
  __syncthreads();
  for (int n = threadIdx.x; n < N; n += 256){
    float acc = bias ? bias[n] : 0.f;
    const float* wr = W + (size_t)n*K;
    for (int k=0; k<K; k++) acc += as[k]*wr[k];
    C[(size_t)row*N + n] = acc;
  }
}

// ---------------- gather q rows for top queries ----------------
__global__ __launch_bounds__(256) void qred_kernel(const unsigned short* __restrict__ q, const int* __restrict__ top,
    float* __restrict__ qred, int L, int u, int n){
  int i = blockIdx.x*256 + threadIdx.x;
  if (i >= n) return;
  int d = i & 63; int rest = i >> 6; int j = rest % u; int bh = rest / u;
  int hh = bh & 7; int b = bh >> 3;
  int pos = top[bh*u + j];
  qred[i] = b2f(q[((size_t)b*L + pos)*DM + hh*DH + d]);
}

// =======================================================================
// flash_attn: fused QK^T -> online softmax -> PV, key-split partials.
// =======================================================================
#define FKT 128
__global__ __launch_bounds__(256) void flash_attn(const float* __restrict__ qred,
    const unsigned short* __restrict__ kbuf, const unsigned short* __restrict__ vbuf,
    float* __restrict__ partM, float* __restrict__ partL, float* __restrict__ partA,
    int L, int u, int KS){
  int ks = blockIdx.x, bh = blockIdx.y; int b = bh >> 3, h = bh & 7;
  int t = threadIdx.x;
  __shared__ float Qs[38*64];
  __shared__ unsigned short Ks[FKT*64];
  __shared__ unsigned short Vs[FKT*64];
  __shared__ float Ss[38*FKT];
  for (int i=t;i<u*64;i+=256) Qs[i] = qred[(size_t)bh*u*64 + i];
  int lane = t & 63, w = t >> 6;
  float rm[10], rl[10], racc[10];
#pragma unroll
  for (int j=0;j<10;j++){ rm[j]=-1e30f; rl[j]=0.f; racc[j]=0.f; }
  int nk = L / KS;
  int kbase = ks*nk;
  int key = t & 127, rh = t >> 7;
  for (int kt = 0; kt < nk; kt += FKT){
    __syncthreads();
    for (int e = t; e < FKT*8; e += 256){
      int k = e >> 3, c = e & 7;
      size_t gidx = ((size_t)(b*L + kbase + kt + k))*DM + h*DH + c*8;
      *(uint4*)((char*)Ks + (size_t)(k*8 + (c ^ (k&7)))*16) = *(const uint4*)(kbuf + gidx);
      *(uint4*)((char*)Vs + (size_t)e*16) = *(const uint4*)(vbuf + gidx);
    }
    __syncthreads();
    for (int r = rh; r < u; r += 2){
      const float4* q4 = (const float4*)(Qs + r*64);
      float acc = 0.f;
#pragma unroll
      for (int c=0;c<8;c++){
        short8 kk = *(const short8*)((char*)Ks + (size_t)(key*8 + (c ^ (key&7)))*16);
        float4 qa = q4[c*2], qb = q4[c*2+1];
        acc += qa.x*b2f((unsigned short)kk[0]) + qa.y*b2f((unsigned short)kk[1])
             + qa.z*b2f((unsigned short)kk[2]) + qa.w*b2f((unsigned short)kk[3]);
        acc += qb.x*b2f((unsigned short)kk[4]) + qb.y*b2f((unsigned short)kk[5])
             + qb.z*b2f((unsigned short)kk[6]) + qb.w*b2f((unsigned short)kk[7]);
      }
      Ss[r*FKT + key] = acc * 0.125f;
    }
    __syncthreads();
    int j = 0;
    for (int r = w; r < u; r += 4, j++){
      float s0 = Ss[r*FKT + lane], s1 = Ss[r*FKT + 64 + lane];
      float mx = fmaxf(s0, s1);
#pragma unroll
      for (int off=32; off; off>>=1) mx = fmaxf(mx, __shfl_xor(mx, off));
      float newm = fmaxf(rm[j], mx);
      float scale = expf(rm[j] - newm);
      float p0 = expf(s0 - newm), p1 = expf(s1 - newm);
      float ps = p0 + p1;
#pragma unroll
      for (int off=32; off; off>>=1) ps += __shfl_xor(ps, off);
      rl[j] = rl[j]*scale + ps;
      rm[j] = newm;
      Ss[r*FKT + lane] = p0; Ss[r*FKT + 64 + lane] = p1;
      float a = racc[j]*scale;
      for (int k=0;k<FKT;k+=4){
        float pa = Ss[r*FKT+k], pb = Ss[r*FKT+k+1], pc = Ss[r*FKT+k+2], pd = Ss[r*FKT+k+3];
        a += pa*b2f(Vs[(k+0)*64+lane]) + pb*b2f(Vs[(k+1)*64+lane])
           + pc*b2f(Vs[(k+2)*64+lane]) + pd*b2f(Vs[(k+3)*64+lane]);
      }
      racc[j] = a;
    }
  }
  int j = 0;
  for (int r = w; r < u; r += 4, j++){
    size_t base = ((size_t)bh*KS + ks)*u + r;
    if (lane == 0){ partM[base] = rm[j]; partL[base] = rl[j]; }
    partA[base*64 + lane] = racc[j];
  }
}

// ---------------- merge key-split partials -> ctxt ----------------
__global__ __launch_bounds__(256) void flash_merge(const float* __restrict__ partM, const float* __restrict__ partL,
    const float* __restrict__ partA, float* __restrict__ ctxt, int u, int KS, int n){
  int i = blockIdx.x*256 + threadIdx.x;
  if (i >= n) return;
  int nn = i & 63; int rest = i >> 6; int r = rest % u; int bhl = rest / u;
  size_t base0 = ((size_t)bhl*KS)*u + r;
  float gm = -1e30f;
  for (int s=0;s<KS;s++) gm = fmaxf(gm, partM[base0 + (size_t)s*u]);
  float lt = 0.f, at = 0.f;
  for (int s=0;s<KS;s++){
    float e = expf(partM[base0 + (size_t)s*u] - gm);
    lt += partL[base0 + (size_t)s*u]*e;
    at += partA[(base0 + (size_t)s*u)*64 + nn]*e;
  }
  ctxt[i] = at / lt;
}

// ---------------- sparse correction: h[b,pos] += (ctxt - vmean_slice)@wo_slice^T ----------------
__global__ __launch_bounds__(256) void scatter_delta(const float* __restrict__ ctxt, const float* __restrict__ vmean,
    const float* __restrict__ wo, const int* __restrict__ top, float* __restrict__ h, int L, int u){
  int bid = blockIdx.x;
  int j = bid % u; int bh = bid / u; int hh = bh & 7; int b = bh >> 3;
  int pos = top[bh*u + j];
  __shared__ float delta[DH];
  int t = threadIdx.x;
  if (t < DH) delta[t] = ctxt[(size_t)(bh*u + j)*DH + t] - vmean[b*DM + hh*DH + t];
  __syncthreads();
  float* hrow = h + ((size_t)b*L + pos)*DM;
  const float* wbase = wo + hh*DH;
  for (int n = t; n < DM; n += 256){
    float acc = 0.f;
    const float* wr = wbase + (size_t)n*DM;
#pragma unroll
    for (int dd=0; dd<DH; dd++) acc += delta[dd] * wr[dd];
    atomicAdd(&hrow[n], acc);
  }
}

// ---------------- LayerNorm D=512; optional +cw[b], +Yadd; out fp32/bf16 ----------------
__global__ __launch_bounds__(256) void ln_kernel(const float* __restrict__ X, const void* __restrict__ Yadd,
    int yb, const float* __restrict__ g, const float* __restrict__ bta, void* __restrict__ Out, int ob,
    const float* __restrict__ cwv, int Lrow, int row0g){
  size_t row = blockIdx.x;
  const float* xr = X + row*DM;
  int t = threadIdx.x;
  float v0 = xr[t], v1 = xr[t+256];
  if (cwv){
    int b = (int)((row0g + (int)row) / Lrow);
    v0 += cwv[b*DM + t]; v1 += cwv[b*DM + t+256];
  }
  if (Yadd){
    if (yb){ const unsigned short* yr = (const unsigned short*)Yadd + row*DM; v0 += b2f(yr[t]); v1 += b2f(yr[t+256]); }
    else   { const float* yr = (const float*)Yadd + row*DM; v0 += yr[t]; v1 += yr[t+256]; }
  }
  float s = v0+v1, q = v0*v0+v1*v1;
#pragma unroll
  for (int off=32; off; off>>=1){ s += __shfl_xor(s,off); q += __shfl_xor(q,off); }
  __shared__ float ss[4], qq[4];
  int w = t >> 6;
  if ((t & 63) == 0){ ss[w] = s; qq[w] = q; }
  __syncthreads();
  s = ss[0]+ss[1]+ss[2]+ss[3]; q = qq[0]+qq[1]+qq[2]+qq[3];
  float mu  = s * (1.0f/DM);
  float var = q * (1.0f/DM) - mu*mu;
  float r = rsqrtf(var + 1e-5f);
  float o0 = (v0 - mu)*r*g[t]     + bta[t];
  float o1 = (v1 - mu)*r*g[t+256] + bta[t+256];
  if (ob){
    unsigned short* Ob = (unsigned short*)Out;
    Ob[row*DM + t] = f2b(o0); Ob[row*DM + t+256] = f2b(o1);
  } else {
    float* Of = (float*)Out;
    Of[row*DM + t] = o0; Of[row*DM + t+256] = o1;
  }
}

// ---------------- BN partial sums over bf16 conv output ----------------
__global__ __launch_bounds__(256) void bnstat1(const unsigned short* __restrict__ C, float* __restrict__ partS,
                                               float* __restrict__ partQ, int rpb){
  int chb = blockIdx.x;
  int mb  = blockIdx.y;
  int g = threadIdx.x >> 6, c = threadIdx.x & 63;
  int ch = chb*64 + c;
  float s = 0.f, q = 0.f;
  int r0 = mb * rpb;
  for (int r = r0 + g; r < r0 + rpb; r += 4){
    float v = b2f(C[(size_t)r*DM + ch]); s += v; q += v*v;
  }
  __shared__ float ls[4][64], lq[4][64];
  ls[g][c] = s; lq[g][c] = q;
  __syncthreads();
  if (g == 0){
    s = ls[0][c]+ls[1][c]+ls[2][c]+ls[3][c];
    q = lq[0][c]+lq[1][c]+lq[2][c]+lq[3][c];
    partS[(size_t)mb*DM + ch] = s;
    partQ[(size_t)mb*DM + ch] = q;
  }
}
__global__ __launch_bounds__(256) void bnstat2(const float* __restrict__ partS, const float* __restrict__ partQ,
                                               float* __restrict__ stats, int NB, int M){
  int ch = blockIdx.x*256 + threadIdx.x;
  if (ch >= DM) return;
  float s = 0.f, q = 0.f;
  for (int mb=0; mb<NB; mb++){
    s += partS[(size_t)mb*DM + ch];
    q += partQ[(size_t)mb*DM + ch];
  }
  float mu = s / (float)M;
  stats[ch] = mu;
  stats[DM + ch] = q / (float)M - mu*mu;
}

// ---------------- BN + ELU + maxpool(3,2) ----------------
__global__ __launch_bounds__(256) void bnpool(const unsigned short* __restrict__ C, const float* __restrict__ stats,
    const float* __restrict__ g, const float* __restrict__ bta, float* __restrict__ Out,
    int L, int Lo){
  size_t i = (size_t)blockIdx.x*256 + threadIdx.x;
  int ch = (int)(i % DM);
  size_t r = i / DM;
  int lo = (int)(r % Lo);
  int b  = (int)(r / Lo);
  float mu = stats[ch];
  float rstd = rsqrtf(stats[DM+ch] + 1e-5f);
  float gg = g[ch], bb = bta[ch];
  float best = -1e30f;
#pragma unroll
  for (int t=-1; t<=1; t++){
    int li = 2*lo + t;
    if (li >= 0 && li < L){
      float v = (b2f(C[((size_t)b*L + li)*DM + ch]) - mu)*rstd*gg + bb;
      v = v > 0.f ? v : expm1f(v);
      best = fmaxf(best, v);
    }
  }
  Out[((size_t)b*Lo + lo)*DM + ch] = best;
}

// ---------------- final: LN(last row) @ proj^T + proj_b + skip ----------------
__global__ __launch_bounds__(128) void final_kernel(const float* __restrict__ h, const float* __restrict__ x,
    const float* __restrict__ fg, const float* __restrict__ fb, const float* __restrict__ pw,
    const float* __restrict__ pb, const float* __restrict__ sw, const float* __restrict__ sb,
    float* __restrict__ out, int Lf, int L0){
  int b = blockIdx.x;
  const float* row = h + ((size_t)b*Lf + (Lf-1))*DM;
  __shared__ float xn[DM];
  __shared__ float rs[2], rq[2];
  int t = threadIdx.x;
  float v[4]; float s = 0.f, q = 0.f;
#pragma unroll
  for (int i=0;i<4;i++){ v[i] = row[t + i*128]; s += v[i]; q += v[i]*v[i]; }
#pragma unroll
  for (int off=32; off; off>>=1){ s += __shfl_xor(s,off); q += __shfl_xor(q,off); }
  if ((t & 63) == 0){ rs[t>>6] = s; rq[t>>6] = q; }
  __syncthreads();
  s = rs[0]+rs[1]; q = rq[0]+rq[1];
  float mu = s*(1.0f/DM), var = q*(1.0f/DM) - mu*mu;
  float r = rsqrtf(var + 1e-5f);
#pragma unroll
  for (int i=0;i<4;i++){ int d = t + i*128; xn[d] = (v[i]-mu)*r*fg[d] + fb[d]; }
  __syncthreads();
  if (t < 96){
    float acc = pb[t] + sb[t];
    const float* xr = x + ((size_t)b*L0 + (L0-1))*7;
#pragma unroll
    for (int c=0;c<7;c++) acc += xr[c]*sw[t*7+c];
    for (int d=0; d<DM; d++) acc += xn[d]*pw[(size_t)t*DM + d];
    out[b*96 + t] = acc;
  }
}

// =======================================================================
extern "C" void kernel_launch(void* const* d_in, const int* in_sizes, int n_in,
                              void* d_out, int out_size, void* d_ws, size_t ws_size,
                              hipStream_t stream){
  const float* x    = (const float*)d_in[0];
  const float* skw  = (const float*)d_in[1];
  const float* skb  = (const float*)d_in[2];
  const float* tcw  = (const float*)d_in[3];
  const float* wq   = (const float*)d_in[4];
  const float* bq   = (const float*)d_in[5];
  const float* wk   = (const float*)d_in[6];
  const float* bk   = (const float*)d_in[7];
  const float* wv   = (const float*)d_in[8];
  const float* bv   = (const float*)d_in[9];
  const float* wo   = (const float*)d_in[10];
  const float* bo   = (const float*)d_in[11];
  const float* w1   = (const float*)d_in[12];
  const float* b1   = (const float*)d_in[13];
  const float* w2   = (const float*)d_in[14];
  const float* b2   = (const float*)d_in[15];
  const float* ln1g = (const float*)d_in[16];
  const float* ln1b = (const float*)d_in[17];
  const float* ln2g = (const float*)d_in[18];
  const float* ln2b = (const float*)d_in[19];
  const float* dcw  = (const float*)d_in[20];
  const float* dcb  = (const float*)d_in[21];
  const float* bng  = (const float*)d_in[22];
  const float* bnb  = (const float*)d_in[23];
  const float* flg  = (const float*)d_in[24];
  const float* flb  = (const float*)d_in[25];
  const float* pw   = (const float*)d_in[26];
  const float* pb   = (const float*)d_in[27];

  const int B = 32, L0 = 2048, DFF = 2048;
  const int RG = 16384;
  const int RF = 8192;
  char* ws = (char*)d_ws;
  const size_t SZH  = (size_t)B*L0*DM*sizeof(float);
  const size_t SLOT = (size_t)RG*DM*sizeof(unsigned short);

  const size_t WBSZ = (size_t)(3*DM*DM + 2*DFF*DM + 3*DM*DM)*2;
  const size_t NCAND = (size_t)256*8*40;
  size_t small_bytes = (size_t)L0*40*4
                     + (size_t)RG*8*4
                     + (size_t)B*8*40*4
                     + (size_t)32*8*40*64*4      // qred_loc
                     + (size_t)32*8*40*64*4      // ctxt_all
                     + 3*(size_t)B*DM*4
                     + 2*(size_t)128*DM*4
                     + (size_t)2*DM*4
                     + (size_t)1536*4
                     + (size_t)B*CMC*DM*4
                     + (size_t)L0*DM*4
                     + (size_t)21*DM*4
                     + 2*NCAND*4;
  if (ws_size < SZH + 4*SLOT + WBSZ + small_bytes) return;

  float*          h   = (float*)(ws);
  unsigned short* P0  = (unsigned short*)(ws + SZH);
  unsigned short* P1  = (unsigned short*)(ws + SZH + SLOT);
  unsigned short* P2  = (unsigned short*)(ws + SZH + 2*SLOT);
  unsigned short* P3  = (unsigned short*)(ws + SZH + 3*SLOT);
  unsigned short* wb  = (unsigned short*)(ws + SZH + 4*SLOT);
  unsigned short* wqb = wb;
  unsigned short* w1b = wqb + (size_t)3*DM*DM;
  unsigned short* w2b = w1b + (size_t)DFF*DM;
  unsigned short* wtapK= w2b + (size_t)DM*DFF;
  char* sm = ws + SZH + 4*SLOT + WBSZ;
  int*   idx_buf  = (int*)sm;
  float* m_buf    = (float*)(sm + (size_t)L0*40*4);
  int*   top_all  = (int*)((char*)m_buf + (size_t)RG*8*4);
  float* qred_loc = (float*)((char*)top_all + (size_t)B*8*40*4);
  float* ctxt_all = qred_loc + (size_t)32*8*40*64;
  float* hm       = ctxt_all + (size_t)32*8*40*64;
  float* vmean    = hm + (size_t)B*DM;
  float* cw       = vmean + (size_t)B*DM;
  float* partS    = cw + (size_t)B*DM;
  float* partQ    = partS + (size_t)128*DM;
  float* stats    = partQ + (size_t)128*DM;
  float* bqkv     = stats + (size_t)2*DM;
  float* partC    = bqkv + (size_t)1536;
  float* pe_buf   = partC + (size_t)B*CMC*DM;
  float* tcwT     = pe_buf + (size_t)L0*DM;
  float* cvalB    = tcwT + (size_t)21*DM;
  int*   cidxB    = (int*)(cvalB + NCAND);

  // flash partials live in P0 (free during attention)
  float* fpM = (float*)P0;
  float* fpL = fpM + (size_t)64*8*40;
  float* fpA = fpL + (size_t)64*8*40;

  auto conv_b = [&](const float* src, unsigned short* dst, size_t n){
    f2b_vec<<<(int)((n/4 + 255)/256), 256, 0, stream>>>(src, dst, (int)(n/4));
  };

  pe_kernel<<<(int)(((size_t)L0*DM)/256), 256, 0, stream>>>(pe_buf, L0);
  packtcw<<<(21*DM + 255)/256, 256, 0, stream>>>(tcw, tcwT);
  embed2<<<B*L0, 256, 0, stream>>>(x, tcwT, pe_buf, h, L0);

  int L = L0;
  for (int layer = 0; layer < 3; layer++){
    int M = B * L;
    int u = (int)(5.0 * log((double)L + 1.0));   // 38 / 34 / 31
    int G = RG / L;
    int nG = M / RG;
    int KS = L / 512;                            // 4 / 2 / 1 key-splits
    const float* wv_i = wv + (size_t)layer*DM*DM;  const float* bv_i = bv + (size_t)layer*DM;
    const float* wo_i = wo + (size_t)layer*DM*DM;  const float* bo_i = bo + (size_t)layer*DM;
    const float* b1_i = b1 + (size_t)layer*DFF;
    const float* b2_i = b2 + (size_t)layer*DM;

    conv_b(wq + (size_t)layer*DM*DM, wqb,                    (size_t)DM*DM);
    conv_b(wk + (size_t)layer*DM*DM, wqb + (size_t)DM*DM,    (size_t)DM*DM);
    conv_b(wv_i,                     wqb + (size_t)2*DM*DM,  (size_t)DM*DM);
    conv_b(w1 + (size_t)layer*DFF*DM, w1b, (size_t)DFF*DM);
    conv_b(w2 + (size_t)layer*DM*DFF, w2b, (size_t)DM*DFF);
    catb_kernel<<<6, 256, 0, stream>>>(bq + (size_t)layer*DM, bk + (size_t)layer*DM, bv_i, bqkv);
    if (layer < 2)
      packconv<<<(3*DM*DM + 255)/256, 256, 0, stream>>>(dcw + (size_t)layer*DM*DM*3, wtapK);

    unsigned ka = 0u, kb2 = (unsigned)layer;
    tf2x32(0u, 42u, ka, kb2);
    unsigned a0 = 0u, a1 = 2u;  tf2x32(ka, kb2, a0, a1);
    unsigned c0 = 1u, c1 = 3u;  tf2x32(ka, kb2, c0, c1);
    int S2 = L * u / 2;
    idx_kernel<<<(S2 + 255)/256, 256, 0, stream>>>(idx_buf, a1, c1, S2, L-1);

    // vmean/cw (exact fp32 identity)
    colmean1<<<dim3(B, CMC), 256, 0, stream>>>(h, partC, L);
    colmean2<<<B*DM/256, 256, 0, stream>>>(partC, hm, L);
    tiny_gemm<<<B, 256, 0, stream>>>(hm, wv_i, bv_i, vmean, DM, DM);
    tiny_gemm<<<B, 256, 0, stream>>>(vmean, wo_i, bo_i, cw, DM, DM);

    for (int g = 0; g < nG; g++){
      const float* hg = h + (size_t)g*RG*DM;
      bgemm2<128,1><<<dim3(12, RG/128), 256, 0, stream>>>(hg, wqb, bqkv, P1,
          1536, 512, L, 0, 0, 1, 1, (size_t)RG*DM, 1);
      sample_m2<<<RG/4, 256, 0, stream>>>(P1, P2, idx_buf, m_buf, L, u);
      int* top_g = top_all + (size_t)g*G*8*u;
      topkA<<<dim3(G*8, 8), 256, 0, stream>>>(m_buf, cvalB, cidxB, L, u);
      topkB<<<G*8, 256, 0, stream>>>(cvalB, cidxB, top_g, u);
      int nqr = G*8*u*DH;
      qred_kernel<<<(nqr + 255)/256, 256, 0, stream>>>(P1, top_g, qred_loc, L, u, nqr);

      flash_attn<<<dim3(KS, G*8), 256, 0, stream>>>(qred_loc, P2, P3, fpM, fpL, fpA, L, u, KS);
      int nmg = G*8*u*64;
      flash_merge<<<(nmg + 255)/256, 256, 0, stream>>>(fpM, fpL, fpA,
          ctxt_all + (size_t)g*G*8*u*64, u, KS, nmg);
    }

    scatter_delta<<<B*8*u, 256, 0, stream>>>(ctxt_all, vmean, wo_i, top_all, h, L, u);

    // FFN: LN1(+cw) -> bf16 ybuf -> FFN1(GELU) -> FFN2 -> LN2(+cw) in-place on h
    unsigned short* ybuf = P0;
    unsigned short* mid  = P1;
    unsigned short* y2b  = P0 + (size_t)RF*DM;
    const float* l1g = ln1g + (size_t)layer*DM; const float* l1b = ln1b + (size_t)layer*DM;
    const float* l2g = ln2g + (size_t)layer*DM; const float* l2b = ln2b + (size_t)layer*DM;
    for (int r0 = 0; r0 < M; r0 += RF){
      ln_kernel<<<RF, 256, 0, stream>>>(h + (size_t)r0*DM, nullptr, 0, l1g, l1b, ybuf, 1, cw, L, r0);
      bgemm2<128,0><<<dim3(16, RF/128), 256, 0, stream>>>(ybuf, w1b, b1_i, mid,
          2048, 512, L, 0, 1, 1, 0, 0, 1);
      bgemm2<64,0><<<dim3(8, RF/128), 256, 0, stream>>>(mid, w2b, b2_i, y2b,
          512, 2048, L, 0, 0, 1, 0, 0, 1);
      ln_kernel<<<RF, 256, 0, stream>>>(h + (size_t)r0*DM, y2b, 1, l2g, l2b, h + (size_t)r0*DM, 0, cw, L, r0);
    }

    if (layer < 2){
      const float* db = dcb + (size_t)layer*DM;
      unsigned short* convb = P0;
      bgemm2<64,1><<<dim3(8, M/128), 256, 0, stream>>>(h, wtapK, db, convb,
          512, 1536, L, 1, 0, 1, 0, 0, 1);
      bnstat1<<<dim3(8, 128), 256, 0, stream>>>(convb, partS, partQ, M/128);
      bnstat2<<<2, 256, 0, stream>>>(partS, partQ, stats, 128, M);
      int Lo = L/2;
      bnpool<<<(int)(((size_t)B*Lo*DM)/256), 256, 0, stream>>>(convb, stats,
          bng + (size_t)layer*DM, bnb + (size_t)layer*DM, h, L, Lo);
      L = Lo;
    }
  }

  final_kernel<<<B, 128, 0, stream>>>(h, x, flg, flb, pw, pb, skw, skb, (float*)d_out, L, L0);
}